// Round 6
// baseline (2168.047 us; speedup 1.0000x reference)
//
#include <hip/hip_runtime.h>
#include <math.h>

#define T_LEN 2048
#define DM    2048
#define NH    16
#define HD    128
#define CDIM  6144
#define GH    768
#define NOUT  24576

typedef unsigned short bf16_t;
typedef unsigned int   uint32;
typedef __attribute__((ext_vector_type(8))) short short8;
typedef __attribute__((ext_vector_type(4))) float f32x4;

__device__ __forceinline__ float silu_f(float v) { return v / (1.f + __expf(-v)); }

__device__ __forceinline__ bf16_t f2bf(float f) {
    uint32 u = __float_as_uint(f);
    u = (u + 0x7fff + ((u >> 16) & 1)) >> 16;   // RNE
    return (bf16_t)u;
}
__device__ __forceinline__ float bf2f(bf16_t b) {
    return __uint_as_float(((uint32)b) << 16);
}
__device__ __forceinline__ uint32 pack2f(float a, float b) {
    return (uint32)f2bf(a) | ((uint32)f2bf(b) << 16);
}

// async global->LDS, 16B per lane; LDS dest = wave-uniform base + lane*16
#define GLL(gptr, lptr) \
  __builtin_amdgcn_global_load_lds((const __attribute__((address_space(1))) void*)(gptr), \
                                   (__attribute__((address_space(3))) void*)(lptr), 16, 0, 0)

// ---------------------------------------------------------------------------
// Transpose + cast: W [K][N] fp32 -> Wt [N][K] bf16
// ---------------------------------------------------------------------------
__global__ __launch_bounds__(256)
void tcast(const float* __restrict__ W, bf16_t* __restrict__ Wt, int K, int N)
{
    __shared__ float tile[32][33];
    const int n0 = blockIdx.x * 32, k0 = blockIdx.y * 32;
    const int c = threadIdx.x & 31, r = threadIdx.x >> 5;
#pragma unroll
    for (int i = 0; i < 4; i++)
        tile[r + i * 8][c] = W[(size_t)(k0 + r + i * 8) * N + n0 + c];
    __syncthreads();
#pragma unroll
    for (int i = 0; i < 4; i++)
        Wt[(size_t)(n0 + r + i * 8) * K + k0 + c] = f2bf(tile[c][r + i * 8]);
}

// elementwise fp32 -> bf16 (4 per thread)
__global__ __launch_bounds__(256)
void castk(const float* __restrict__ in, bf16_t* __restrict__ out, int n4)
{
    int i = blockIdx.x * 256 + threadIdx.x;
    if (i >= n4) return;
    float4 v = ((const float4*)in)[i];
    uint2 p;
    p.x = pack2f(v.x, v.y);
    p.y = pack2f(v.z, v.w);
    ((uint2*)out)[i] = p;
}

// ---------------------------------------------------------------------------
// bf16 MFMA GEMM (m97 structure): C[M,N] = A[M,K] @ Bt[N,K]^T
// ---------------------------------------------------------------------------
template<int EPI, int NPER>
__global__ __launch_bounds__(256)
void mgemm(const bf16_t* __restrict__ A, const bf16_t* __restrict__ Bt,
           float* __restrict__ C, bf16_t* __restrict__ C16,
           int M, int N, int K)
{
    __shared__ bf16_t As[4096];
    __shared__ bf16_t Bs[4096];
    const int tid = threadIdx.x;
    const int lane = tid & 63, w = tid >> 6;
    const int quad = lane >> 4, tl = lane & 15;
    int bm0, bn0;
    if (NPER == 0) { bm0 = blockIdx.y * 128; bn0 = blockIdx.x * 128; }
    else {
        int bx = blockIdx.x, xcd = bx & 7, seq = bx >> 3;
        bm0 = (seq & 15) * 128;
        bn0 = (xcd * NPER + (seq >> 4)) * 128;
    }
    const int wm = (w >> 1) * 64, wn = (w & 1) * 64;

    const bf16_t* a0 = A  + (size_t)(bm0 + (tid & 127)) * K + ((tid >> 7) << 3);
    const bf16_t* b0 = Bt + (size_t)(bn0 + (tid & 127)) * K + ((tid >> 7) << 3);
    bf16_t* asd0 = &As[w * 512];
    bf16_t* asd1 = &As[2048 + w * 512];
    bf16_t* bsd0 = &Bs[w * 512];
    bf16_t* bsd1 = &Bs[2048 + w * 512];

    f32x4 acc[4][4];
#pragma unroll
    for (int i = 0; i < 4; i++)
#pragma unroll
        for (int j = 0; j < 4; j++) { acc[i][j][0] = 0.f; acc[i][j][1] = 0.f; acc[i][j][2] = 0.f; acc[i][j][3] = 0.f; }

    for (int k0 = 0; k0 < K; k0 += 32) {
        __syncthreads();
        GLL(a0 + k0,      asd0);
        GLL(a0 + k0 + 16, asd1);
        GLL(b0 + k0,      bsd0);
        GLL(b0 + k0 + 16, bsd1);
        __syncthreads();
        short8 af[4], bfr[4];
#pragma unroll
        for (int mt = 0; mt < 4; mt++)
            af[mt] = *(const short8*)&As[(quad * 128 + wm + mt * 16 + tl) * 8];
#pragma unroll
        for (int nt = 0; nt < 4; nt++)
            bfr[nt] = *(const short8*)&Bs[(quad * 128 + wn + nt * 16 + tl) * 8];
#pragma unroll
        for (int mt = 0; mt < 4; mt++)
#pragma unroll
            for (int nt = 0; nt < 4; nt++)
                acc[mt][nt] = __builtin_amdgcn_mfma_f32_16x16x32_bf16(af[mt], bfr[nt], acc[mt][nt], 0, 0, 0);
    }

#pragma unroll
    for (int mt = 0; mt < 4; mt++) {
        int rbase = bm0 + wm + mt * 16 + quad * 4;
#pragma unroll
        for (int nt = 0; nt < 4; nt++) {
            int cg = bn0 + wn + nt * 16 + tl;
#pragma unroll
            for (int r = 0; r < 4; r++) {
                float v = acc[mt][nt][r];
                size_t idx = (size_t)(rbase + r) * N + cg;
                if (EPI == 0)      C[idx]   = v;
                else if (EPI == 1) C16[idx] = f2bf(v);
                else               C16[idx] = f2bf(silu_f(v));
            }
        }
    }
}

// ---------------------------------------------------------------------------
// convgen: kern = h1 @ gen_w2 + b2 (MFMA), fused causal W=4 conv + silu.
// ---------------------------------------------------------------------------
__global__ __launch_bounds__(256)
void convgen(const bf16_t* __restrict__ A, const bf16_t* __restrict__ Bt,
             const float* __restrict__ b2, const bf16_t* __restrict__ u16c,
             float* __restrict__ cvout)
{
    const int K = GH;
    __shared__ __align__(16) char smraw[36864];
    bf16_t* As = (bf16_t*)smraw;
    bf16_t* Bs = As + 4096;
    float* uf   = (float*)smraw;              // [131][36]  (epilogue overlay)
    float* outs = (float*)(smraw + 18880);    // [128][33]

    const int tid = threadIdx.x;
    const int lane = tid & 63, w = tid >> 6;
    const int quad = lane >> 4, tl = lane & 15;
    const int bx = blockIdx.x, xcd = bx & 7, seq = bx >> 3;
    const int bm0 = (seq & 15) * 128;
    const int bn0 = (xcd * 24 + (seq >> 4)) * 128;
    const int wm = (w >> 1) * 64, wn = (w & 1) * 64;

    const bf16_t* a0 = A  + (size_t)(bm0 + (tid & 127)) * K + ((tid >> 7) << 3);
    const bf16_t* b0 = Bt + (size_t)(bn0 + (tid & 127)) * K + ((tid >> 7) << 3);
    bf16_t* asd0 = &As[w * 512];
    bf16_t* asd1 = &As[2048 + w * 512];
    bf16_t* bsd0 = &Bs[w * 512];
    bf16_t* bsd1 = &Bs[2048 + w * 512];

    f32x4 acc[4][4];
#pragma unroll
    for (int i = 0; i < 4; i++)
#pragma unroll
        for (int j = 0; j < 4; j++) { acc[i][j][0] = 0.f; acc[i][j][1] = 0.f; acc[i][j][2] = 0.f; acc[i][j][3] = 0.f; }

    for (int k0 = 0; k0 < K; k0 += 32) {
        __syncthreads();
        GLL(a0 + k0,      asd0);
        GLL(a0 + k0 + 16, asd1);
        GLL(b0 + k0,      bsd0);
        GLL(b0 + k0 + 16, bsd1);
        __syncthreads();
        short8 af[4], bfr[4];
#pragma unroll
        for (int mt = 0; mt < 4; mt++)
            af[mt] = *(const short8*)&As[(quad * 128 + wm + mt * 16 + tl) * 8];
#pragma unroll
        for (int nt = 0; nt < 4; nt++)
            bfr[nt] = *(const short8*)&Bs[(quad * 128 + wn + nt * 16 + tl) * 8];
#pragma unroll
        for (int mt = 0; mt < 4; mt++)
#pragma unroll
            for (int nt = 0; nt < 4; nt++)
                acc[mt][nt] = __builtin_amdgcn_mfma_f32_16x16x32_bf16(af[mt], bfr[nt], acc[mt][nt], 0, 0, 0);
    }
    __syncthreads();   // fragments consumed; overlay As/Bs with uf/outs

    const int d0 = bn0 >> 2;
    for (int i = tid; i < 131 * 8; i += 256) {
        int row = i >> 3, seg = i & 7;
        int t = bm0 - 3 + row;
        float* dst = &uf[row * 36 + seg * 4];
        if (t >= 0) {
            uint2 p = *(const uint2*)&u16c[(size_t)t * CDIM + d0 + seg * 4];
            dst[0] = bf2f((bf16_t)(p.x & 0xffff));
            dst[1] = bf2f((bf16_t)(p.x >> 16));
            dst[2] = bf2f((bf16_t)(p.y & 0xffff));
            dst[3] = bf2f((bf16_t)(p.y >> 16));
        } else {
            dst[0] = 0.f; dst[1] = 0.f; dst[2] = 0.f; dst[3] = 0.f;
        }
    }
    __syncthreads();

    const int wi = tl & 3;
#pragma unroll
    for (int nt = 0; nt < 4; nt++) {
        int n = bn0 + wn + nt * 16 + tl;
        float b2v = b2[n];
        int dloc = (wn >> 2) + nt * 4 + (tl >> 2);
#pragma unroll
        for (int mt = 0; mt < 4; mt++) {
            int trl = wm + mt * 16 + quad * 4;
#pragma unroll
            for (int r = 0; r < 4; r++) {
                float p = (acc[mt][nt][r] + b2v) * uf[(trl + r + wi) * 36 + dloc];
                p += __shfl_xor(p, 1);
                p += __shfl_xor(p, 2);
                if (wi == 0) outs[(trl + r) * 33 + dloc] = p;
            }
        }
    }
    __syncthreads();

    for (int i = tid; i < 4096; i += 256) {
        int row = i >> 5, col = i & 31;
        cvout[(size_t)(bm0 + row) * CDIM + d0 + col] = silu_f(outs[row * 33 + col]);
    }
}

// ---------------------------------------------------------------------------
// ba: beta=sigmoid(b), decay=sigmoid(-a); outputs transposed [H][T]
// ---------------------------------------------------------------------------
__global__ __launch_bounds__(256)
void ba_kernel(const float* __restrict__ x, const float* __restrict__ Wba,
               float* __restrict__ betaT, float* __restrict__ decT)
{
    const int t = blockIdx.x * 8 + (threadIdx.x >> 5);
    const int c = threadIdx.x & 31;
    const float* xr = x + (size_t)t * DM;
    float acc = 0.f;
#pragma unroll 4
    for (int k0 = 0; k0 < DM; k0 += 4) {
        float4 xv = *(const float4*)&xr[k0];
        acc = fmaf(xv.x, Wba[(k0 + 0) * 32 + c], acc);
        acc = fmaf(xv.y, Wba[(k0 + 1) * 32 + c], acc);
        acc = fmaf(xv.z, Wba[(k0 + 2) * 32 + c], acc);
        acc = fmaf(xv.w, Wba[(k0 + 3) * 32 + c], acc);
    }
    float val = 1.f / (1.f + __expf((c < 16) ? -acc : acc));
    if (c < 16) betaT[(size_t)c * T_LEN + t] = val;
    else        decT[(size_t)(c - 16) * T_LEN + t] = val;
}

// ===========================================================================
// Chunked gated delta rule (UT transform), L = 64.
// Phase 1: per-chunk parallel; stores all phase-2 operands in oct-major
// swizzled layouts so phase 2 can GLL-stage them linearly with MFMA-ready,
// conflict-free LDS addressing:
//   P_W : off(s,k)  = ((k>>3)*64 +s)*8 + (k&7)     (8192 / chunk)
//   P_KT: off(dk,s) = ((s>>3)*128+dk)*8 + (s&7)    (8192)
//   P_D : off(t,s)  = ((s>>3)*64 +t)*8 + (s&7)     (4096)
//   Qn  : off(t,k)  = ((k>>3)*64 +t)*8 + (k&7)     (8192)
//   P_U1T: exact phase-2 per-thread read order: g*4096 + tid*16 + tj*4 + r
//   P_aL: exp(cs[63]) per chunk.
// Phase 2: 32 blocks, serial over 32 chunks; W/K/D double-buffered via GLL
// prefetch; Q/U/aL double-buffered in registers -> global latency off the
// serial chain.
// ===========================================================================
__global__ __launch_bounds__(256)
void dr_phase1(const float* __restrict__ cv, const float* __restrict__ decT,
               const float* __restrict__ betaT,
               bf16_t* __restrict__ P_W, bf16_t* __restrict__ P_U1T,
               bf16_t* __restrict__ P_KT, bf16_t* __restrict__ P_D,
               float* __restrict__ P_aL, bf16_t* __restrict__ Qn)
{
    __shared__ float kfn[64 * 132];     // normalized k, fp32
    __shared__ float A_ls[64 * 68];     // A[s][r]
    __shared__ bf16_t D16s[64 * 68];    // D staging (bf16)
    __shared__ float csL[64], betaL[64], eaL[64], ebL[64], rnk[64];

    const int ch = blockIdx.x, h = ch >> 5, c = ch & 31;
    const int t0 = c * 64;
    const int tid = threadIdx.x, w = tid >> 6, lane = tid & 63;
    const int quad = lane >> 4, tl = lane & 15;

    const float* kg = cv + (size_t)t0 * CDIM + NH * HD + h * HD;
    const float* qg = cv + (size_t)t0 * CDIM + h * HD;
    const float* vg = cv + (size_t)t0 * CDIM + 2 * NH * HD + h * HD;

    // --- stage raw k into LDS (fp32) ---
#pragma unroll
    for (int i = 0; i < 8; i++) {
        int idx = tid + 256 * i;
        int t = idx >> 5, c4 = (idx & 31) * 4;
        *(float4*)&kfn[t * 132 + c4] = *(const float4*)&kg[(size_t)t * CDIM + c4];
    }
    // --- cumulative log decay, beta, exp tables ---
    if (tid < 64) {
        float dec = decT[(size_t)h * T_LEN + t0 + tid];
        float csum = __logf(dec);
#pragma unroll
        for (int off = 1; off < 64; off <<= 1) {
            float o = __shfl_up(csum, off);
            if (tid >= off) csum += o;
        }
        csL[tid]   = csum;
        eaL[tid]   = __expf(csum);
        betaL[tid] = betaT[(size_t)h * T_LEN + t0 + tid];
        float c63 = __shfl(csum, 63);
        ebL[tid]  = __expf(c63 - csum);
    }
    __syncthreads();
    if (tid == 63) P_aL[ch] = __expf(csL[63]);

    // --- k row norms (4 threads/row) ---
    {
        int t = tid >> 2, p = tid & 3;
        float ss = 0.f;
#pragma unroll
        for (int j = 0; j < 8; j++) {
            float4 v = *(const float4*)&kfn[t * 132 + p * 32 + j * 4];
            ss += v.x * v.x + v.y * v.y + v.z * v.z + v.w * v.w;
        }
        ss += __shfl_xor(ss, 1);
        ss += __shfl_xor(ss, 2);
        if (p == 0) rnk[t] = rsqrtf(ss + 1e-6f);
    }
    __syncthreads();
#pragma unroll
    for (int i = 0; i < 8; i++) {
        int idx = tid + 256 * i;
        int t = idx >> 5, c4 = (idx & 31) * 4;
        float4 v = *(float4*)&kfn[t * 132 + c4];
        float rs = rnk[t];
        v.x *= rs; v.y *= rs; v.z *= rs; v.w *= rs;
        *(float4*)&kfn[t * 132 + c4] = v;
    }
    __syncthreads();

    // --- q: load, normalize in regs, emit frags + Qn (swizzled) ---
    const int row = 16 * w + tl;
    float qv[4][8];
    float ssq = 0.f;
#pragma unroll
    for (int kk = 0; kk < 4; kk++) {
        const float* qp = &qg[(size_t)row * CDIM + 32 * kk + 8 * quad];
        *(float4*)&qv[kk][0] = *(const float4*)qp;
        *(float4*)&qv[kk][4] = *(const float4*)(qp + 4);
#pragma unroll
        for (int j = 0; j < 8; j++) ssq += qv[kk][j] * qv[kk][j];
    }
    ssq += __shfl_xor(ssq, 16);
    ssq += __shfl_xor(ssq, 32);
    const float qsc = rsqrtf(ssq + 1e-6f) * 0.08838834764831845f;
    const float qe  = qsc * eaL[row];

    short8 xqh[4], xql[4], xkh[4], xkl[4];
    {
        bf16_t* Qch = Qn + (size_t)ch * 8192;
#pragma unroll
        for (int kk = 0; kk < 4; kk++) {
            short8 qn8;
#pragma unroll
            for (int j = 0; j < 8; j++) {
                float qx = qv[kk][j] * qsc;
                bf16_t hh = f2bf(qx);
                xqh[kk][j] = (short)hh;
                xql[kk][j] = (short)f2bf(qx - bf2f(hh));
                qn8[j] = (short)f2bf(qv[kk][j] * qe);
            }
            *(short8*)&Qch[((4 * kk + quad) * 64 + row) * 8] = qn8;
        }
#pragma unroll
        for (int kk = 0; kk < 4; kk++) {
            float kv[8];
            *(float4*)&kv[0] = *(const float4*)&kfn[row * 132 + 32 * kk + 8 * quad];
            *(float4*)&kv[4] = *(const float4*)&kfn[row * 132 + 32 * kk + 8 * quad + 4];
#pragma unroll
            for (int j = 0; j < 8; j++) {
                bf16_t hh = f2bf(kv[j]);
                xkh[kk][j] = (short)hh;
                xkl[kk][j] = (short)f2bf(kv[j] - bf2f(hh));
            }
        }
    }

    // --- KK^T and QK^T (split-bf16, 2-term) ---
    f32x4 aK[4], aQ[4];
#pragma unroll
    for (int j = 0; j < 4; j++)
#pragma unroll
        for (int r = 0; r < 4; r++) { aK[j][r] = 0.f; aQ[j][r] = 0.f; }
#pragma unroll
    for (int tj = 0; tj < 4; tj++) {
#pragma unroll
        for (int kk = 0; kk < 4; kk++) {
            float yv[8];
            int yoff = (16 * tj + tl) * 132 + 32 * kk + 8 * quad;
            *(float4*)&yv[0] = *(const float4*)&kfn[yoff];
            *(float4*)&yv[4] = *(const float4*)&kfn[yoff + 4];
            short8 yh, yl;
#pragma unroll
            for (int j = 0; j < 8; j++) {
                bf16_t hh = f2bf(yv[j]);
                yh[j] = (short)hh;
                yl[j] = (short)f2bf(yv[j] - bf2f(hh));
            }
            aK[tj] = __builtin_amdgcn_mfma_f32_16x16x32_bf16(xkh[kk], yh, aK[tj], 0, 0, 0);
            aK[tj] = __builtin_amdgcn_mfma_f32_16x16x32_bf16(xkh[kk], yl, aK[tj], 0, 0, 0);
            aK[tj] = __builtin_amdgcn_mfma_f32_16x16x32_bf16(xkl[kk], yh, aK[tj], 0, 0, 0);
            aQ[tj] = __builtin_amdgcn_mfma_f32_16x16x32_bf16(xqh[kk], yh, aQ[tj], 0, 0, 0);
            aQ[tj] = __builtin_amdgcn_mfma_f32_16x16x32_bf16(xqh[kk], yl, aQ[tj], 0, 0, 0);
            aQ[tj] = __builtin_amdgcn_mfma_f32_16x16x32_bf16(xql[kk], yh, aQ[tj], 0, 0, 0);
        }
    }
    // --- epilogue: A (LDS fp32) and D (LDS bf16) ---
#pragma unroll
    for (int tj = 0; tj < 4; tj++) {
#pragma unroll
        for (int r = 0; r < 4; r++) {
            int s  = 16 * w + 4 * quad + r;
            int rr = 16 * tj + tl;
            float e = __expf(csL[s] - csL[rr]);
            A_ls[s * 68 + rr] = (s > rr) ? betaL[s] * e * aK[tj][r] : 0.f;
            D16s[s * 68 + rr] = (s >= rr) ? f2bf(e * aQ[tj][r]) : (bf16_t)0;
        }
    }
    __syncthreads();

    // --- forward substitution: (I+A) u = b, 256 RHS columns ---
    float bb[64];
    if (tid < 128) {
        int j = tid;
#pragma unroll
        for (int s = 0; s < 64; s++) bb[s] = betaL[s] * vg[(size_t)s * CDIM + j];
    } else {
        int dk = tid - 128;
#pragma unroll
        for (int s = 0; s < 64; s++)
            bb[s] = betaL[s] * eaL[s] * kfn[s * 132 + dk];
    }
#pragma unroll
    for (int r4 = 0; r4 < 64; r4 += 4) {
        float u0 = bb[r4];
        float u1 = bb[r4 + 1] - A_ls[(r4 + 1) * 68 + r4] * u0;
        float u2 = bb[r4 + 2] - A_ls[(r4 + 2) * 68 + r4] * u0 - A_ls[(r4 + 2) * 68 + r4 + 1] * u1;
        float u3 = bb[r4 + 3] - A_ls[(r4 + 3) * 68 + r4] * u0 - A_ls[(r4 + 3) * 68 + r4 + 1] * u1
                              - A_ls[(r4 + 3) * 68 + r4 + 2] * u2;
        bb[r4] = u0; bb[r4 + 1] = u1; bb[r4 + 2] = u2; bb[r4 + 3] = u3;
#pragma unroll
        for (int s = r4 + 4; s < 64; s++) {
            float4 a4 = *(const float4*)&A_ls[s * 68 + r4];
            bb[s] -= a4.x * u0 + a4.y * u1 + a4.z * u2 + a4.w * u3;
        }
    }

    // --- K store (swizzled; reads kfn) ---
    {
        uint32* gK = (uint32*)(P_KT + (size_t)ch * 8192);
#pragma unroll
        for (int i = 0; i < 16; i++) {
            int u = tid * 16 + i;                     // [0,4096)
            int soct = u >> 9, dk = (u >> 2) & 127, s = soct * 8 + (u & 3) * 2;
            gK[u] = pack2f(ebL[s] * kfn[s * 132 + dk], ebL[s + 1] * kfn[(s + 1) * 132 + dk]);
        }
    }
    // --- D store (swizzled; reads D16s) ---
    {
        uint32* gD = (uint32*)(P_D + (size_t)ch * 4096);
#pragma unroll
        for (int i = 0; i < 8; i++) {
            int u = tid * 8 + i;                      // [0,2048)
            int soct = u >> 8, t = (u >> 2) & 63, s = soct * 8 + (u & 3) * 2;
            gD[u] = (uint32)D16s[t * 68 + s] | ((uint32)D16s[t * 68 + s + 1] << 16);
        }
    }
    __syncthreads();   // kfn/A_ls reads done; safe to clobber
    // --- stage W (fp32, kfn region) and U (bf16, A_ls region) ---
    float* wtmp = kfn;
    bf16_t* uS = (bf16_t*)A_ls;
    if (tid < 128) {
        int g2 = tid >> 6, vloc = tid & 63;
        int base = g2 * 4096 + (vloc >> 4) * 1024 + ((vloc >> 2) & 3) * 256 + (vloc & 3);
#pragma unroll
        for (int s = 0; s < 64; s++)
            uS[base + (s & 15) * 16 + (s >> 4) * 4] = f2bf(bb[s]);
    } else {
        int dk = tid - 128;
#pragma unroll
        for (int s = 0; s < 64; s++) wtmp[s * 132 + dk] = bb[s];
    }
    __syncthreads();
    // --- W store (swizzled) + U store (linear copy of staged order) ---
    {
        uint32* gW = (uint32*)(P_W + (size_t)ch * 8192);
#pragma unroll
        for (int i = 0; i < 16; i++) {
            int u = tid * 16 + i;                     // [0,4096)
            int koct = u >> 8, s = (u >> 2) & 63, k = koct * 8 + (u & 3) * 2;
            gW[u] = pack2f(wtmp[s * 132 + k], wtmp[s * 132 + k + 1]);
        }
        uint32* gU = (uint32*)(P_U1T + (size_t)ch * 8192);
        const uint32* uS32 = (const uint32*)uS;
#pragma unroll
        for (int i = 0; i < 16; i++) gU[tid * 16 + i] = uS32[tid * 16 + i];
    }
}

__global__ __launch_bounds__(256, 1)
void dr_phase2(const bf16_t* __restrict__ Qn,
               const bf16_t* __restrict__ P_W, const bf16_t* __restrict__ P_U1T,
               const bf16_t* __restrict__ P_KT, const bf16_t* __restrict__ P_D,
               const float* __restrict__ P_aL, bf16_t* __restrict__ o16)
{
    __shared__ bf16_t Ws[2][8192];
    __shared__ bf16_t Ks[2][8192];
    __shared__ bf16_t Ds[2][4096];
    __shared__ unsigned short Z16[64 * 136];
    __shared__ unsigned short uT16[64 * 72];

    const int h = blockIdx.x >> 1, g = blockIdx.x & 1, vbase = g * 64;
    const int tid = threadIdx.x, w = tid >> 6, lane = tid & 63;
    const int quad = lane >> 4, tl = lane & 15;
    const int trow = 16 * w + tl;

    for (int i = tid; i < 64 * 136 / 2; i += 256) ((uint32*)Z16)[i] = 0;

    f32x4 Zacc[8];
#pragma unroll
    for (int i = 0; i < 8; i++)
#pragma unroll
        for (int r = 0; r < 4; r++) Zacc[i][r] = 0.f;

    short8 qpf[2][4];
    short8 upf[2][2];
    float aLr[2];

    // prefetch chunk 0
    {
        const bf16_t* gp = P_W + (size_t)(h * 32) * 8192;
#pragma unroll
        for (int i = 0; i < 4; i++) GLL(gp + (w * 4 + i) * 512 + lane * 8, &Ws[0][(w * 4 + i) * 512]);
        gp = P_KT + (size_t)(h * 32) * 8192;
#pragma unroll
        for (int i = 0; i < 4; i++) GLL(gp + (w * 4 + i) * 512 + lane * 8, &Ks[0][(w * 4 + i) * 512]);
        gp = P_D + (size_t)(h * 32) * 4096;
#pragma unroll
        for (int i = 0; i < 2; i++) GLL(gp + (w * 2 + i) * 512 + lane * 8, &Ds[0][(w * 2 + i) * 512]);
        const bf16_t* pQ = Qn + (size_t)(h * 32) * 8192;
#pragma unroll
        for (int kk = 0; kk < 4; kk++) qpf[0][kk] = *(const short8*)&pQ[((4 * kk + quad) * 64 + trow) * 8];
        const bf16_t* pU = P_U1T + (size_t)(h * 32) * 8192 + g * 4096 + tid * 16;
        upf[0][0] = *(const short8*)&pU[0];
        upf[0][1] = *(const short8*)&pU[8];
        aLr[0] = P_aL[h * 32];
    }
    __syncthreads();

    for (int c = 0; c < 32; c++) {
        const int s = c & 1;
        const int t0c = c * 64;

        // ---- uT = U1 - Z (.) W  ([v][s]) ----
        f32x4 au[4];
#pragma unroll
        for (int j = 0; j < 4; j++)
#pragma unroll
            for (int r = 0; r < 4; r++) au[j][r] = 0.f;
        short8 zf[4];
#pragma unroll
        for (int kk = 0; kk < 4; kk++)
            zf[kk] = *(const short8*)&Z16[trow * 136 + 32 * kk + 8 * quad];
#pragma unroll
        for (int tj = 0; tj < 4; tj++)
#pragma unroll
            for (int kk = 0; kk < 4; kk++) {
                short8 wf = *(const short8*)&Ws[s][((4 * kk + quad) * 64 + 16 * tj + tl) * 8];
                au[tj] = __builtin_amdgcn_mfma_f32_16x16x32_bf16(zf[kk], wf, au[tj], 0, 0, 0);
            }
#pragma unroll
        for (int tj = 0; tj < 4; tj++)
#pragma unroll
            for (int r = 0; r < 4; r++) {
                int v = 16 * w + 4 * quad + r, sc = 16 * tj + tl;
                int idx = tj * 4 + r;
                float u1 = bf2f((bf16_t)(unsigned short)upf[s][idx >> 3][idx & 7]);
                uT16[v * 72 + sc] = f2bf(u1 - au[tj][r]);
            }
        __syncthreads();

        // prefetch W/Q/U/aL for chunk c+1 (drains by next barrier; off chain)
        if (c + 1 < 32) {
            const int cn = h * 32 + c + 1, sn = s ^ 1;
            const bf16_t* gp = P_W + (size_t)cn * 8192;
#pragma unroll
            for (int i = 0; i < 4; i++) GLL(gp + (w * 4 + i) * 512 + lane * 8, &Ws[sn][(w * 4 + i) * 512]);
            const bf16_t* pQ = Qn + (size_t)cn * 8192;
#pragma unroll
            for (int kk = 0; kk < 4; kk++) qpf[sn][kk] = *(const short8*)&pQ[((4 * kk + quad) * 64 + trow) * 8];
            const bf16_t* pU = P_U1T + (size_t)cn * 8192 + g * 4096 + tid * 16;
            upf[sn][0] = *(const short8*)&pU[0];
            upf[sn][1] = *(const short8*)&pU[8];
            aLr[sn] = P_aL[cn];
        }

        // ---- o = Qn (.) Z + D (.) uT  ([t][v]) ----
        f32x4 ao[4];
#pragma unroll
        for (int j = 0; j < 4; j++)
#pragma unroll
            for (int r = 0; r < 4; r++) ao[j][r] = 0.f;
#pragma unroll
        for (int kk = 0; kk < 4; kk++) {
#pragma unroll
            for (int tj = 0; tj < 4; tj++) {
                short8 zb = *(const short8*)&Z16[(16 * tj + tl) * 136 + 32 * kk + 8 * quad];
                ao[tj] = __builtin_amdgcn_mfma_f32_16x16x32_bf16(qpf[s][kk], zb, ao[tj], 0, 0, 0);
            }
        }
#pragma unroll
        for (int k2 = 0; k2 < 2; k2++) {
            short8 df = *(const short8*)&Ds[s][((4 * k2 + quad) * 64 + trow) * 8];
#pragma unroll
            for (int tj = 0; tj < 4; tj++) {
                short8 ub = *(const short8*)&uT16[(16 * tj + tl) * 72 + 32 * k2 + 8 * quad];
                ao[tj] = __builtin_amdgcn_mfma_f32_16x16x32_bf16(df, ub, ao[tj], 0, 0, 0);
            }
        }
#pragma unroll
        for (int tj = 0; tj < 4; tj++)
#pragma unroll
            for (int r = 0; r < 4; r++) {
                int t = 16 * w + 4 * quad + r, v = 16 * tj + tl;
                o16[(size_t)(t0c + t) * DM + h * HD + vbase + v] = f2bf(ao[tj][r]);
            }
        __syncthreads();   // all Z16/uT16 reads done

        // prefetch K/D for chunk c+1
        if (c + 1 < 32) {
            const int cn = h * 32 + c + 1, sn = s ^ 1;
            const bf16_t* gp = P_KT + (size_t)cn * 8192;
#pragma unroll
            for (int i = 0; i < 4; i++) GLL(gp + (w * 4 + i) * 512 + lane * 8, &Ks[sn][(w * 4 + i) * 512]);
            gp = P_D + (size_t)cn * 4096;
#pragma unroll
            for (int i = 0; i < 2; i++) GLL(gp + (w * 2 + i) * 512 + lane * 8, &Ds[sn][(w * 2 + i) * 512]);
        }

        // ---- Z = aL*Z + uT (.) KhatT  ([v][dk]) ----
        float aL = aLr[s];
#pragma unroll
        for (int td = 0; td < 8; td++)
#pragma unroll
            for (int r = 0; r < 4; r++) Zacc[td][r] *= aL;
#pragma unroll
        for (int k2 = 0; k2 < 2; k2++) {
            short8 uf = *(const short8*)&uT16[trow * 72 + 32 * k2 + 8 * quad];
#pragma unroll
            for (int td = 0; td < 8; td++) {
                short8 kf = *(const short8*)&Ks[s][((4 * k2 + quad) * 128 + 16 * td + tl) * 8];
                Zacc[td] = __builtin_amdgcn_mfma_f32_16x16x32_bf16(uf, kf, Zacc[td], 0, 0, 0);
            }
        }
#pragma unroll
        for (int td = 0; td < 8; td++)
#pragma unroll
            for (int r = 0; r < 4; r++) {
                int v = 16 * w + 4 * quad + r, dk = 16 * td + tl;
                Z16[v * 136 + dk] = f2bf(Zacc[td][r]);
            }
        __syncthreads();
    }
}

// ---------------------------------------------------------------------------
// Workspace layout (float offsets), 116.65 MB total (same proven footprint):
//   cv    [0, 12582912)
//   P_W [12582912,+2097152) P_U1T [14680064,+2097152) P_KT [16777216,+2097152)
//   h116  [18874368, 19660800)
//   decT  [19660800,+32768)  betaT [19693568,+32768)
//   wT    [19726336,+9437184): gw2T etc; after convgen:
//       P_D [19726336,+1048576) P_aL [20774912,+512) WoT [20807680,+2097152)
//       o16 [22904832,+2097152)  Qn [25001984,+2097152)
// ---------------------------------------------------------------------------
extern "C" void kernel_launch(void* const* d_in, const int* in_sizes, int n_in,
                              void* d_out, int out_size, void* d_ws, size_t ws_size,
                              hipStream_t stream)
{
    const float* x      = (const float*)d_in[0];
    const float* W_qkv  = (const float*)d_in[1];
    const float* W_ba   = (const float*)d_in[2];
    const float* gen_w1 = (const float*)d_in[3];
    const float* gen_w2 = (const float*)d_in[4];
    const float* gen_b2 = (const float*)d_in[5];
    const float* W_o    = (const float*)d_in[6];
    float* y  = (float*)d_out;
    float* wsf = (float*)d_ws;

    float*  cv    = wsf;
    bf16_t* x16   = (bf16_t*)wsf;
    bf16_t* u16   = (bf16_t*)(wsf + 12582912);
    bf16_t* h116  = (bf16_t*)(wsf + 18874368);
    float*  decT  = wsf + 19660800;
    float*  betaT = wsf + 19693568;
    bf16_t* wT    = (bf16_t*)(wsf + 19726336);
    bf16_t* P_W   = (bf16_t*)(wsf + 12582912);
    bf16_t* P_U1T = (bf16_t*)(wsf + 14680064);
    bf16_t* P_KT  = (bf16_t*)(wsf + 16777216);
    bf16_t* P_D   = (bf16_t*)(wsf + 19726336);
    float*  P_aL  = wsf + 20774912;
    bf16_t* WoT   = (bf16_t*)(wsf + 20807680);
    bf16_t* o16   = (bf16_t*)(wsf + 22904832);
    bf16_t* Qn    = (bf16_t*)(wsf + 25001984);

    dim3 blk(256);

    tcast<<<dim3(192, 64), blk, 0, stream>>>(W_qkv, wT, DM, CDIM);
    castk<<<dim3(4096), blk, 0, stream>>>(x, x16, (T_LEN * DM) / 4);
    mgemm<1, 6><<<dim3(768), blk, 0, stream>>>(x16, wT, nullptr, u16, T_LEN, CDIM, DM);
    ba_kernel<<<dim3(256), blk, 0, stream>>>(x, W_ba, betaT, decT);
    tcast<<<dim3(24, 192), blk, 0, stream>>>(gen_w1, wT, CDIM, GH);
    mgemm<2, 0><<<dim3(6, 16), blk, 0, stream>>>(u16, wT, nullptr, h116, T_LEN, GH, CDIM);
    tcast<<<dim3(768, 24), blk, 0, stream>>>(gen_w2, wT, GH, NOUT);
    convgen<<<dim3(3072), blk, 0, stream>>>(h116, wT, gen_b2, u16, cv);
    dr_phase1<<<dim3(512), blk, 0, stream>>>(cv, decT, betaT, P_W, P_U1T, P_KT, P_D, P_aL, Qn);
    tcast<<<dim3(64, 64), blk, 0, stream>>>(W_o, WoT, DM, DM);
    dr_phase2<<<dim3(32), blk, 0, stream>>>(Qn, P_W, P_U1T, P_KT, P_D, P_aL, o16);
    mgemm<0, 2><<<dim3(256), blk, 0, stream>>>(o16, WoT, y, nullptr, T_LEN, DM, DM);
}

// Round 7
// 935.495 us; speedup vs baseline: 2.3175x; 2.3175x over previous
//
#include <hip/hip_runtime.h>
#include <math.h>

#define T_LEN 2048
#define DM    2048
#define NH    16
#define HD    128
#define CDIM  6144
#define GH    768
#define NOUT  24576

typedef unsigned short bf16_t;
typedef unsigned int   uint32;
typedef __attribute__((ext_vector_type(8))) short short8;
typedef __attribute__((ext_vector_type(4))) float f32x4;

__device__ __forceinline__ float silu_f(float v) { return v / (1.f + __expf(-v)); }

__device__ __forceinline__ bf16_t f2bf(float f) {
    uint32 u = __float_as_uint(f);
    u = (u + 0x7fff + ((u >> 16) & 1)) >> 16;   // RNE
    return (bf16_t)u;
}
__device__ __forceinline__ float bf2f(bf16_t b) {
    return __uint_as_float(((uint32)b) << 16);
}
__device__ __forceinline__ uint32 pack2f(float a, float b) {
    return (uint32)f2bf(a) | ((uint32)f2bf(b) << 16);
}

// async global->LDS, 16B per lane; LDS dest = wave-uniform base + lane*16
#define GLL(gptr, lptr) \
  __builtin_amdgcn_global_load_lds((const __attribute__((address_space(1))) void*)(gptr), \
                                   (__attribute__((address_space(3))) void*)(lptr), 16, 0, 0)

// ---------------------------------------------------------------------------
// Transpose + cast: W [K][N] fp32 -> Wt [N][K] bf16
// ---------------------------------------------------------------------------
__global__ __launch_bounds__(256)
void tcast(const float* __restrict__ W, bf16_t* __restrict__ Wt, int K, int N)
{
    __shared__ float tile[32][33];
    const int n0 = blockIdx.x * 32, k0 = blockIdx.y * 32;
    const int c = threadIdx.x & 31, r = threadIdx.x >> 5;
#pragma unroll
    for (int i = 0; i < 4; i++)
        tile[r + i * 8][c] = W[(size_t)(k0 + r + i * 8) * N + n0 + c];
    __syncthreads();
#pragma unroll
    for (int i = 0; i < 4; i++)
        Wt[(size_t)(n0 + r + i * 8) * K + k0 + c] = f2bf(tile[c][r + i * 8]);
}

// elementwise fp32 -> bf16 (4 per thread)
__global__ __launch_bounds__(256)
void castk(const float* __restrict__ in, bf16_t* __restrict__ out, int n4)
{
    int i = blockIdx.x * 256 + threadIdx.x;
    if (i >= n4) return;
    float4 v = ((const float4*)in)[i];
    uint2 p;
    p.x = pack2f(v.x, v.y);
    p.y = pack2f(v.z, v.w);
    ((uint2*)out)[i] = p;
}

// ---------------------------------------------------------------------------
// bf16 MFMA GEMM (m97 structure): C[M,N] = A[M,K] @ Bt[N,K]^T
// ---------------------------------------------------------------------------
template<int EPI, int NPER>
__global__ __launch_bounds__(256)
void mgemm(const bf16_t* __restrict__ A, const bf16_t* __restrict__ Bt,
           float* __restrict__ C, bf16_t* __restrict__ C16,
           int M, int N, int K)
{
    __shared__ bf16_t As[4096];
    __shared__ bf16_t Bs[4096];
    const int tid = threadIdx.x;
    const int lane = tid & 63, w = tid >> 6;
    const int quad = lane >> 4, tl = lane & 15;
    int bm0, bn0;
    if (NPER == 0) { bm0 = blockIdx.y * 128; bn0 = blockIdx.x * 128; }
    else {
        int bx = blockIdx.x, xcd = bx & 7, seq = bx >> 3;
        bm0 = (seq & 15) * 128;
        bn0 = (xcd * NPER + (seq >> 4)) * 128;
    }
    const int wm = (w >> 1) * 64, wn = (w & 1) * 64;

    const bf16_t* a0 = A  + (size_t)(bm0 + (tid & 127)) * K + ((tid >> 7) << 3);
    const bf16_t* b0 = Bt + (size_t)(bn0 + (tid & 127)) * K + ((tid >> 7) << 3);
    bf16_t* asd0 = &As[w * 512];
    bf16_t* asd1 = &As[2048 + w * 512];
    bf16_t* bsd0 = &Bs[w * 512];
    bf16_t* bsd1 = &Bs[2048 + w * 512];

    f32x4 acc[4][4];
#pragma unroll
    for (int i = 0; i < 4; i++)
#pragma unroll
        for (int j = 0; j < 4; j++) { acc[i][j][0] = 0.f; acc[i][j][1] = 0.f; acc[i][j][2] = 0.f; acc[i][j][3] = 0.f; }

    for (int k0 = 0; k0 < K; k0 += 32) {
        __syncthreads();
        GLL(a0 + k0,      asd0);
        GLL(a0 + k0 + 16, asd1);
        GLL(b0 + k0,      bsd0);
        GLL(b0 + k0 + 16, bsd1);
        __syncthreads();
        short8 af[4], bfr[4];
#pragma unroll
        for (int mt = 0; mt < 4; mt++)
            af[mt] = *(const short8*)&As[(quad * 128 + wm + mt * 16 + tl) * 8];
#pragma unroll
        for (int nt = 0; nt < 4; nt++)
            bfr[nt] = *(const short8*)&Bs[(quad * 128 + wn + nt * 16 + tl) * 8];
#pragma unroll
        for (int mt = 0; mt < 4; mt++)
#pragma unroll
            for (int nt = 0; nt < 4; nt++)
                acc[mt][nt] = __builtin_amdgcn_mfma_f32_16x16x32_bf16(af[mt], bfr[nt], acc[mt][nt], 0, 0, 0);
    }

#pragma unroll
    for (int mt = 0; mt < 4; mt++) {
        int rbase = bm0 + wm + mt * 16 + quad * 4;
#pragma unroll
        for (int nt = 0; nt < 4; nt++) {
            int cg = bn0 + wn + nt * 16 + tl;
#pragma unroll
            for (int r = 0; r < 4; r++) {
                float v = acc[mt][nt][r];
                size_t idx = (size_t)(rbase + r) * N + cg;
                if (EPI == 0)      C[idx]   = v;
                else if (EPI == 1) C16[idx] = f2bf(v);
                else               C16[idx] = f2bf(silu_f(v));
            }
        }
    }
}

// ---------------------------------------------------------------------------
// convgen: kern = h1 @ gen_w2 + b2 (MFMA), fused causal W=4 conv + silu.
// ---------------------------------------------------------------------------
__global__ __launch_bounds__(256)
void convgen(const bf16_t* __restrict__ A, const bf16_t* __restrict__ Bt,
             const float* __restrict__ b2, const bf16_t* __restrict__ u16c,
             float* __restrict__ cvout)
{
    const int K = GH;
    __shared__ __align__(16) char smraw[36864];
    bf16_t* As = (bf16_t*)smraw;
    bf16_t* Bs = As + 4096;
    float* uf   = (float*)smraw;              // [131][36]  (epilogue overlay)
    float* outs = (float*)(smraw + 18880);    // [128][33]

    const int tid = threadIdx.x;
    const int lane = tid & 63, w = tid >> 6;
    const int quad = lane >> 4, tl = lane & 15;
    const int bx = blockIdx.x, xcd = bx & 7, seq = bx >> 3;
    const int bm0 = (seq & 15) * 128;
    const int bn0 = (xcd * 24 + (seq >> 4)) * 128;
    const int wm = (w >> 1) * 64, wn = (w & 1) * 64;

    const bf16_t* a0 = A  + (size_t)(bm0 + (tid & 127)) * K + ((tid >> 7) << 3);
    const bf16_t* b0 = Bt + (size_t)(bn0 + (tid & 127)) * K + ((tid >> 7) << 3);
    bf16_t* asd0 = &As[w * 512];
    bf16_t* asd1 = &As[2048 + w * 512];
    bf16_t* bsd0 = &Bs[w * 512];
    bf16_t* bsd1 = &Bs[2048 + w * 512];

    f32x4 acc[4][4];
#pragma unroll
    for (int i = 0; i < 4; i++)
#pragma unroll
        for (int j = 0; j < 4; j++) { acc[i][j][0] = 0.f; acc[i][j][1] = 0.f; acc[i][j][2] = 0.f; acc[i][j][3] = 0.f; }

    for (int k0 = 0; k0 < K; k0 += 32) {
        __syncthreads();
        GLL(a0 + k0,      asd0);
        GLL(a0 + k0 + 16, asd1);
        GLL(b0 + k0,      bsd0);
        GLL(b0 + k0 + 16, bsd1);
        __syncthreads();
        short8 af[4], bfr[4];
#pragma unroll
        for (int mt = 0; mt < 4; mt++)
            af[mt] = *(const short8*)&As[(quad * 128 + wm + mt * 16 + tl) * 8];
#pragma unroll
        for (int nt = 0; nt < 4; nt++)
            bfr[nt] = *(const short8*)&Bs[(quad * 128 + wn + nt * 16 + tl) * 8];
#pragma unroll
        for (int mt = 0; mt < 4; mt++)
#pragma unroll
            for (int nt = 0; nt < 4; nt++)
                acc[mt][nt] = __builtin_amdgcn_mfma_f32_16x16x32_bf16(af[mt], bfr[nt], acc[mt][nt], 0, 0, 0);
    }
    __syncthreads();   // fragments consumed; overlay As/Bs with uf/outs

    const int d0 = bn0 >> 2;
    for (int i = tid; i < 131 * 8; i += 256) {
        int row = i >> 3, seg = i & 7;
        int t = bm0 - 3 + row;
        float* dst = &uf[row * 36 + seg * 4];
        if (t >= 0) {
            uint2 p = *(const uint2*)&u16c[(size_t)t * CDIM + d0 + seg * 4];
            dst[0] = bf2f((bf16_t)(p.x & 0xffff));
            dst[1] = bf2f((bf16_t)(p.x >> 16));
            dst[2] = bf2f((bf16_t)(p.y & 0xffff));
            dst[3] = bf2f((bf16_t)(p.y >> 16));
        } else {
            dst[0] = 0.f; dst[1] = 0.f; dst[2] = 0.f; dst[3] = 0.f;
        }
    }
    __syncthreads();

    const int wi = tl & 3;
#pragma unroll
    for (int nt = 0; nt < 4; nt++) {
        int n = bn0 + wn + nt * 16 + tl;
        float b2v = b2[n];
        int dloc = (wn >> 2) + nt * 4 + (tl >> 2);
#pragma unroll
        for (int mt = 0; mt < 4; mt++) {
            int trl = wm + mt * 16 + quad * 4;
#pragma unroll
            for (int r = 0; r < 4; r++) {
                float p = (acc[mt][nt][r] + b2v) * uf[(trl + r + wi) * 36 + dloc];
                p += __shfl_xor(p, 1);
                p += __shfl_xor(p, 2);
                if (wi == 0) outs[(trl + r) * 33 + dloc] = p;
            }
        }
    }
    __syncthreads();

    for (int i = tid; i < 4096; i += 256) {
        int row = i >> 5, col = i & 31;
        cvout[(size_t)(bm0 + row) * CDIM + d0 + col] = silu_f(outs[row * 33 + col]);
    }
}

// ---------------------------------------------------------------------------
// ba: beta=sigmoid(b), decay=sigmoid(-a); outputs transposed [H][T]
// ---------------------------------------------------------------------------
__global__ __launch_bounds__(256)
void ba_kernel(const float* __restrict__ x, const float* __restrict__ Wba,
               float* __restrict__ betaT, float* __restrict__ decT)
{
    const int t = blockIdx.x * 8 + (threadIdx.x >> 5);
    const int c = threadIdx.x & 31;
    const float* xr = x + (size_t)t * DM;
    float acc = 0.f;
#pragma unroll 4
    for (int k0 = 0; k0 < DM; k0 += 4) {
        float4 xv = *(const float4*)&xr[k0];
        acc = fmaf(xv.x, Wba[(k0 + 0) * 32 + c], acc);
        acc = fmaf(xv.y, Wba[(k0 + 1) * 32 + c], acc);
        acc = fmaf(xv.z, Wba[(k0 + 2) * 32 + c], acc);
        acc = fmaf(xv.w, Wba[(k0 + 3) * 32 + c], acc);
    }
    float val = 1.f / (1.f + __expf((c < 16) ? -acc : acc));
    if (c < 16) betaT[(size_t)c * T_LEN + t] = val;
    else        decT[(size_t)(c - 16) * T_LEN + t] = val;
}

// ===========================================================================
// Chunked gated delta rule (UT transform), L = 64.  Same layouts as R5.
// Phase 2 rewritten: chunk loop unrolled by 2 so ALL double-buffer indices
// are compile-time (R5's runtime-indexed register arrays were demoted to
// scratch -> 5x regression). GLL dbuf for shared W/K/D; named register pairs
// (qpf0/qpf1, upf0/upf1, aL0/aL1) for per-thread Q/U/aL.
// ===========================================================================
__global__ __launch_bounds__(256)
void dr_phase1(const float* __restrict__ cv, const float* __restrict__ decT,
               const float* __restrict__ betaT,
               bf16_t* __restrict__ P_W, bf16_t* __restrict__ P_U1T,
               bf16_t* __restrict__ P_KT, bf16_t* __restrict__ P_D,
               float* __restrict__ P_aL, bf16_t* __restrict__ Qn)
{
    __shared__ float kfn[64 * 132];     // normalized k, fp32
    __shared__ float A_ls[64 * 68];     // A[s][r]
    __shared__ bf16_t D16s[64 * 68];    // D staging (bf16)
    __shared__ float csL[64], betaL[64], eaL[64], ebL[64], rnk[64];

    const int ch = blockIdx.x, h = ch >> 5, c = ch & 31;
    const int t0 = c * 64;
    const int tid = threadIdx.x, w = tid >> 6, lane = tid & 63;
    const int quad = lane >> 4, tl = lane & 15;

    const float* kg = cv + (size_t)t0 * CDIM + NH * HD + h * HD;
    const float* qg = cv + (size_t)t0 * CDIM + h * HD;
    const float* vg = cv + (size_t)t0 * CDIM + 2 * NH * HD + h * HD;

    // --- stage raw k into LDS (fp32) ---
#pragma unroll
    for (int i = 0; i < 8; i++) {
        int idx = tid + 256 * i;
        int t = idx >> 5, c4 = (idx & 31) * 4;
        *(float4*)&kfn[t * 132 + c4] = *(const float4*)&kg[(size_t)t * CDIM + c4];
    }
    // --- cumulative log decay, beta, exp tables ---
    if (tid < 64) {
        float dec = decT[(size_t)h * T_LEN + t0 + tid];
        float csum = __logf(dec);
#pragma unroll
        for (int off = 1; off < 64; off <<= 1) {
            float o = __shfl_up(csum, off);
            if (tid >= off) csum += o;
        }
        csL[tid]   = csum;
        eaL[tid]   = __expf(csum);
        betaL[tid] = betaT[(size_t)h * T_LEN + t0 + tid];
        float c63 = __shfl(csum, 63);
        ebL[tid]  = __expf(c63 - csum);
    }
    __syncthreads();
    if (tid == 63) P_aL[ch] = __expf(csL[63]);

    // --- k row norms (4 threads/row) ---
    {
        int t = tid >> 2, p = tid & 3;
        float ss = 0.f;
#pragma unroll
        for (int j = 0; j < 8; j++) {
            float4 v = *(const float4*)&kfn[t * 132 + p * 32 + j * 4];
            ss += v.x * v.x + v.y * v.y + v.z * v.z + v.w * v.w;
        }
        ss += __shfl_xor(ss, 1);
        ss += __shfl_xor(ss, 2);
        if (p == 0) rnk[t] = rsqrtf(ss + 1e-6f);
    }
    __syncthreads();
#pragma unroll
    for (int i = 0; i < 8; i++) {
        int idx = tid + 256 * i;
        int t = idx >> 5, c4 = (idx & 31) * 4;
        float4 v = *(float4*)&kfn[t * 132 + c4];
        float rs = rnk[t];
        v.x *= rs; v.y *= rs; v.z *= rs; v.w *= rs;
        *(float4*)&kfn[t * 132 + c4] = v;
    }
    __syncthreads();

    // --- q: load, normalize in regs, emit frags + Qn (swizzled) ---
    const int row = 16 * w + tl;
    float qv[4][8];
    float ssq = 0.f;
#pragma unroll
    for (int kk = 0; kk < 4; kk++) {
        const float* qp = &qg[(size_t)row * CDIM + 32 * kk + 8 * quad];
        *(float4*)&qv[kk][0] = *(const float4*)qp;
        *(float4*)&qv[kk][4] = *(const float4*)(qp + 4);
#pragma unroll
        for (int j = 0; j < 8; j++) ssq += qv[kk][j] * qv[kk][j];
    }
    ssq += __shfl_xor(ssq, 16);
    ssq += __shfl_xor(ssq, 32);
    const float qsc = rsqrtf(ssq + 1e-6f) * 0.08838834764831845f;
    const float qe  = qsc * eaL[row];

    short8 xqh[4], xql[4], xkh[4], xkl[4];
    {
        bf16_t* Qch = Qn + (size_t)ch * 8192;
#pragma unroll
        for (int kk = 0; kk < 4; kk++) {
            short8 qn8;
#pragma unroll
            for (int j = 0; j < 8; j++) {
                float qx = qv[kk][j] * qsc;
                bf16_t hh = f2bf(qx);
                xqh[kk][j] = (short)hh;
                xql[kk][j] = (short)f2bf(qx - bf2f(hh));
                qn8[j] = (short)f2bf(qv[kk][j] * qe);
            }
            *(short8*)&Qch[((4 * kk + quad) * 64 + row) * 8] = qn8;
        }
#pragma unroll
        for (int kk = 0; kk < 4; kk++) {
            float kv[8];
            *(float4*)&kv[0] = *(const float4*)&kfn[row * 132 + 32 * kk + 8 * quad];
            *(float4*)&kv[4] = *(const float4*)&kfn[row * 132 + 32 * kk + 8 * quad + 4];
#pragma unroll
            for (int j = 0; j < 8; j++) {
                bf16_t hh = f2bf(kv[j]);
                xkh[kk][j] = (short)hh;
                xkl[kk][j] = (short)f2bf(kv[j] - bf2f(hh));
            }
        }
    }

    // --- KK^T and QK^T (split-bf16, 2-term) ---
    f32x4 aK[4], aQ[4];
#pragma unroll
    for (int j = 0; j < 4; j++)
#pragma unroll
        for (int r = 0; r < 4; r++) { aK[j][r] = 0.f; aQ[j][r] = 0.f; }
#pragma unroll
    for (int tj = 0; tj < 4; tj++) {
#pragma unroll
        for (int kk = 0; kk < 4; kk++) {
            float yv[8];
            int yoff = (16 * tj + tl) * 132 + 32 * kk + 8 * quad;
            *(float4*)&yv[0] = *(const float4*)&kfn[yoff];
            *(float4*)&yv[4] = *(const float4*)&kfn[yoff + 4];
            short8 yh, yl;
#pragma unroll
            for (int j = 0; j < 8; j++) {
                bf16_t hh = f2bf(yv[j]);
                yh[j] = (short)hh;
                yl[j] = (short)f2bf(yv[j] - bf2f(hh));
            }
            aK[tj] = __builtin_amdgcn_mfma_f32_16x16x32_bf16(xkh[kk], yh, aK[tj], 0, 0, 0);
            aK[tj] = __builtin_amdgcn_mfma_f32_16x16x32_bf16(xkh[kk], yl, aK[tj], 0, 0, 0);
            aK[tj] = __builtin_amdgcn_mfma_f32_16x16x32_bf16(xkl[kk], yh, aK[tj], 0, 0, 0);
            aQ[tj] = __builtin_amdgcn_mfma_f32_16x16x32_bf16(xqh[kk], yh, aQ[tj], 0, 0, 0);
            aQ[tj] = __builtin_amdgcn_mfma_f32_16x16x32_bf16(xqh[kk], yl, aQ[tj], 0, 0, 0);
            aQ[tj] = __builtin_amdgcn_mfma_f32_16x16x32_bf16(xql[kk], yh, aQ[tj], 0, 0, 0);
        }
    }
    // --- epilogue: A (LDS fp32) and D (LDS bf16) ---
#pragma unroll
    for (int tj = 0; tj < 4; tj++) {
#pragma unroll
        for (int r = 0; r < 4; r++) {
            int s  = 16 * w + 4 * quad + r;
            int rr = 16 * tj + tl;
            float e = __expf(csL[s] - csL[rr]);
            A_ls[s * 68 + rr] = (s > rr) ? betaL[s] * e * aK[tj][r] : 0.f;
            D16s[s * 68 + rr] = (s >= rr) ? f2bf(e * aQ[tj][r]) : (bf16_t)0;
        }
    }
    __syncthreads();

    // --- forward substitution: (I+A) u = b, 256 RHS columns ---
    float bb[64];
    if (tid < 128) {
        int j = tid;
#pragma unroll
        for (int s = 0; s < 64; s++) bb[s] = betaL[s] * vg[(size_t)s * CDIM + j];
    } else {
        int dk = tid - 128;
#pragma unroll
        for (int s = 0; s < 64; s++)
            bb[s] = betaL[s] * eaL[s] * kfn[s * 132 + dk];
    }
#pragma unroll
    for (int r4 = 0; r4 < 64; r4 += 4) {
        float u0 = bb[r4];
        float u1 = bb[r4 + 1] - A_ls[(r4 + 1) * 68 + r4] * u0;
        float u2 = bb[r4 + 2] - A_ls[(r4 + 2) * 68 + r4] * u0 - A_ls[(r4 + 2) * 68 + r4 + 1] * u1;
        float u3 = bb[r4 + 3] - A_ls[(r4 + 3) * 68 + r4] * u0 - A_ls[(r4 + 3) * 68 + r4 + 1] * u1
                              - A_ls[(r4 + 3) * 68 + r4 + 2] * u2;
        bb[r4] = u0; bb[r4 + 1] = u1; bb[r4 + 2] = u2; bb[r4 + 3] = u3;
#pragma unroll
        for (int s = r4 + 4; s < 64; s++) {
            float4 a4 = *(const float4*)&A_ls[s * 68 + r4];
            bb[s] -= a4.x * u0 + a4.y * u1 + a4.z * u2 + a4.w * u3;
        }
    }

    // --- K store (swizzled; reads kfn) ---
    {
        uint32* gK = (uint32*)(P_KT + (size_t)ch * 8192);
#pragma unroll
        for (int i = 0; i < 16; i++) {
            int u = tid * 16 + i;                     // [0,4096)
            int soct = u >> 9, dk = (u >> 2) & 127, s = soct * 8 + (u & 3) * 2;
            gK[u] = pack2f(ebL[s] * kfn[s * 132 + dk], ebL[s + 1] * kfn[(s + 1) * 132 + dk]);
        }
    }
    // --- D store (swizzled; reads D16s) ---
    {
        uint32* gD = (uint32*)(P_D + (size_t)ch * 4096);
#pragma unroll
        for (int i = 0; i < 8; i++) {
            int u = tid * 8 + i;                      // [0,2048)
            int soct = u >> 8, t = (u >> 2) & 63, s = soct * 8 + (u & 3) * 2;
            gD[u] = (uint32)D16s[t * 68 + s] | ((uint32)D16s[t * 68 + s + 1] << 16);
        }
    }
    __syncthreads();   // kfn/A_ls reads done; safe to clobber
    // --- stage W (fp32, kfn region) and U (bf16, A_ls region) ---
    float* wtmp = kfn;
    bf16_t* uS = (bf16_t*)A_ls;
    if (tid < 128) {
        int g2 = tid >> 6, vloc = tid & 63;
        int base = g2 * 4096 + (vloc >> 4) * 1024 + ((vloc >> 2) & 3) * 256 + (vloc & 3);
#pragma unroll
        for (int s = 0; s < 64; s++)
            uS[base + (s & 15) * 16 + (s >> 4) * 4] = f2bf(bb[s]);
    } else {
        int dk = tid - 128;
#pragma unroll
        for (int s = 0; s < 64; s++) wtmp[s * 132 + dk] = bb[s];
    }
    __syncthreads();
    // --- W store (swizzled) + U store (linear copy of staged order) ---
    {
        uint32* gW = (uint32*)(P_W + (size_t)ch * 8192);
#pragma unroll
        for (int i = 0; i < 16; i++) {
            int u = tid * 16 + i;                     // [0,4096)
            int koct = u >> 8, s = (u >> 2) & 63, k = koct * 8 + (u & 3) * 2;
            gW[u] = pack2f(wtmp[s * 132 + k], wtmp[s * 132 + k + 1]);
        }
        uint32* gU = (uint32*)(P_U1T + (size_t)ch * 8192);
        const uint32* uS32 = (const uint32*)uS;
#pragma unroll
        for (int i = 0; i < 16; i++) gU[tid * 16 + i] = uS32[tid * 16 + i];
    }
}

__global__ __launch_bounds__(256, 1)
void dr_phase2(const bf16_t* __restrict__ Qn,
               const bf16_t* __restrict__ P_W, const bf16_t* __restrict__ P_U1T,
               const bf16_t* __restrict__ P_KT, const bf16_t* __restrict__ P_D,
               const float* __restrict__ P_aL, bf16_t* __restrict__ o16)
{
    __shared__ bf16_t Ws[2][8192];
    __shared__ bf16_t Ks[2][8192];
    __shared__ bf16_t Ds[2][4096];
    __shared__ unsigned short Z16[64 * 136];
    __shared__ unsigned short uT16[64 * 72];

    const int h = blockIdx.x >> 1, g = blockIdx.x & 1, vbase = g * 64;
    const int tid = threadIdx.x, w = tid >> 6, lane = tid & 63;
    const int quad = lane >> 4, tl = lane & 15;
    const int trow = 16 * w + tl;

    for (int i = tid; i < 64 * 136 / 2; i += 256) ((uint32*)Z16)[i] = 0;

    f32x4 Zacc[8];
#pragma unroll
    for (int i = 0; i < 8; i++)
#pragma unroll
        for (int r = 0; r < 4; r++) Zacc[i][r] = 0.f;

    short8 qpf0[4], qpf1[4], upf0[2], upf1[2];
    float aL0, aL1;

    // stage chunk 0 into buffers/regs 0
    {
        const int c0 = h * 32;
        const bf16_t* gp = P_W + (size_t)c0 * 8192;
#pragma unroll
        for (int i = 0; i < 4; i++) GLL(gp + (w * 4 + i) * 512 + lane * 8, &Ws[0][(w * 4 + i) * 512]);
        gp = P_KT + (size_t)c0 * 8192;
#pragma unroll
        for (int i = 0; i < 4; i++) GLL(gp + (w * 4 + i) * 512 + lane * 8, &Ks[0][(w * 4 + i) * 512]);
        gp = P_D + (size_t)c0 * 4096;
#pragma unroll
        for (int i = 0; i < 2; i++) GLL(gp + (w * 2 + i) * 512 + lane * 8, &Ds[0][(w * 2 + i) * 512]);
        const bf16_t* pQ = Qn + (size_t)c0 * 8192;
#pragma unroll
        for (int kk = 0; kk < 4; kk++) qpf0[kk] = *(const short8*)&pQ[((4 * kk + quad) * 64 + trow) * 8];
        const bf16_t* pU = P_U1T + (size_t)c0 * 8192 + g * 4096 + tid * 16;
        upf0[0] = *(const short8*)&pU[0];
        upf0[1] = *(const short8*)&pU[8];
        aL0 = P_aL[c0];
    }
    __syncthreads();   // drains chunk-0 staging; Z16 zero visible

    // S = current buffer index (literal), SN = other (literal).
#define CHUNK(C, S, SN)                                                             \
    {                                                                               \
        const int t0c = (C) * 64;                                                   \
        /* prefetch chunk C+1 into buffers/regs SN (drains at barrier below) */     \
        if ((C) + 1 < 32) {                                                         \
            const int cn = h * 32 + (C) + 1;                                        \
            const bf16_t* gp = P_W + (size_t)cn * 8192;                             \
            _Pragma("unroll")                                                       \
            for (int i = 0; i < 4; i++)                                             \
                GLL(gp + (w * 4 + i) * 512 + lane * 8, &Ws[SN][(w * 4 + i) * 512]); \
            gp = P_KT + (size_t)cn * 8192;                                          \
            _Pragma("unroll")                                                       \
            for (int i = 0; i < 4; i++)                                             \
                GLL(gp + (w * 4 + i) * 512 + lane * 8, &Ks[SN][(w * 4 + i) * 512]); \
            gp = P_D + (size_t)cn * 4096;                                           \
            _Pragma("unroll")                                                       \
            for (int i = 0; i < 2; i++)                                             \
                GLL(gp + (w * 2 + i) * 512 + lane * 8, &Ds[SN][(w * 2 + i) * 512]); \
            const bf16_t* pQ = Qn + (size_t)cn * 8192;                              \
            _Pragma("unroll")                                                       \
            for (int kk = 0; kk < 4; kk++)                                          \
                qpf##SN[kk] = *(const short8*)&pQ[((4 * kk + quad) * 64 + trow) * 8]; \
            const bf16_t* pU = P_U1T + (size_t)cn * 8192 + g * 4096 + tid * 16;     \
            upf##SN[0] = *(const short8*)&pU[0];                                    \
            upf##SN[1] = *(const short8*)&pU[8];                                    \
            aL##SN = P_aL[cn];                                                      \
        }                                                                           \
        /* ---- uT = U1 - Z (.) W ---- */                                           \
        f32x4 au[4];                                                                \
        _Pragma("unroll")                                                           \
        for (int j = 0; j < 4; j++)                                                 \
            { au[j][0] = 0.f; au[j][1] = 0.f; au[j][2] = 0.f; au[j][3] = 0.f; }     \
        short8 zf[4];                                                               \
        _Pragma("unroll")                                                           \
        for (int kk = 0; kk < 4; kk++)                                              \
            zf[kk] = *(const short8*)&Z16[trow * 136 + 32 * kk + 8 * quad];         \
        _Pragma("unroll")                                                           \
        for (int tj = 0; tj < 4; tj++)                                              \
            _Pragma("unroll")                                                       \
            for (int kk = 0; kk < 4; kk++) {                                        \
                short8 wf = *(const short8*)&Ws[S][((4 * kk + quad) * 64 + 16 * tj + tl) * 8]; \
                au[tj] = __builtin_amdgcn_mfma_f32_16x16x32_bf16(zf[kk], wf, au[tj], 0, 0, 0); \
            }                                                                       \
        _Pragma("unroll")                                                           \
        for (int tj = 0; tj < 4; tj++)                                              \
            _Pragma("unroll")                                                       \
            for (int r = 0; r < 4; r++) {                                           \
                int v = 16 * w + 4 * quad + r, sc = 16 * tj + tl;                   \
                float u1 = bf2f((bf16_t)(unsigned short)upf##S[(tj * 4 + r) >> 3][(tj * 4 + r) & 7]); \
                uT16[v * 72 + sc] = f2bf(u1 - au[tj][r]);                           \
            }                                                                       \
        __syncthreads();                                                            \
        /* ---- o = Qn (.) Z + D (.) uT ---- */                                     \
        f32x4 ao[4];                                                                \
        _Pragma("unroll")                                                           \
        for (int j = 0; j < 4; j++)                                                 \
            { ao[j][0] = 0.f; ao[j][1] = 0.f; ao[j][2] = 0.f; ao[j][3] = 0.f; }     \
        _Pragma("unroll")                                                           \
        for (int kk = 0; kk < 4; kk++) {                                            \
            _Pragma("unroll")                                                       \
            for (int tj = 0; tj < 4; tj++) {                                        \
                short8 zb = *(const short8*)&Z16[(16 * tj + tl) * 136 + 32 * kk + 8 * quad]; \
                ao[tj] = __builtin_amdgcn_mfma_f32_16x16x32_bf16(qpf##S[kk], zb, ao[tj], 0, 0, 0); \
            }                                                                       \
        }                                                                           \
        _Pragma("unroll")                                                           \
        for (int k2 = 0; k2 < 2; k2++) {                                            \
            short8 df = *(const short8*)&Ds[S][((4 * k2 + quad) * 64 + trow) * 8];  \
            _Pragma("unroll")                                                       \
            for (int tj = 0; tj < 4; tj++) {                                        \
                short8 ub = *(const short8*)&uT16[(16 * tj + tl) * 72 + 32 * k2 + 8 * quad]; \
                ao[tj] = __builtin_amdgcn_mfma_f32_16x16x32_bf16(df, ub, ao[tj], 0, 0, 0); \
            }                                                                       \
        }                                                                           \
        _Pragma("unroll")                                                           \
        for (int tj = 0; tj < 4; tj++)                                              \
            _Pragma("unroll")                                                       \
            for (int r = 0; r < 4; r++) {                                           \
                int t = 16 * w + 4 * quad + r, v = 16 * tj + tl;                    \
                o16[(size_t)(t0c + t) * DM + h * HD + vbase + v] = f2bf(ao[tj][r]); \
            }                                                                       \
        __syncthreads();   /* Z16/uT16 reads done */                                \
        /* ---- Z = aL*Z + uT (.) KhatT ---- */                                     \
        _Pragma("unroll")                                                           \
        for (int td = 0; td < 8; td++)                                              \
            _Pragma("unroll")                                                       \
            for (int r = 0; r < 4; r++) Zacc[td][r] *= aL##S;                       \
        _Pragma("unroll")                                                           \
        for (int k2 = 0; k2 < 2; k2++) {                                            \
            short8 uf = *(const short8*)&uT16[trow * 72 + 32 * k2 + 8 * quad];      \
            _Pragma("unroll")                                                       \
            for (int td = 0; td < 8; td++) {                                        \
                short8 kf = *(const short8*)&Ks[S][((4 * k2 + quad) * 128 + 16 * td + tl) * 8]; \
                Zacc[td] = __builtin_amdgcn_mfma_f32_16x16x32_bf16(uf, kf, Zacc[td], 0, 0, 0); \
            }                                                                       \
        }                                                                           \
        _Pragma("unroll")                                                           \
        for (int td = 0; td < 8; td++)                                              \
            _Pragma("unroll")                                                       \
            for (int r = 0; r < 4; r++) {                                           \
                int v = 16 * w + 4 * quad + r, dk = 16 * td + tl;                   \
                Z16[v * 136 + dk] = f2bf(Zacc[td][r]);                              \
            }                                                                       \
        __syncthreads();                                                            \
    }

    for (int cc = 0; cc < 32; cc += 2) {
        CHUNK(cc, 0, 1);
        CHUNK(cc + 1, 1, 0);
    }
#undef CHUNK
}

// ---------------------------------------------------------------------------
// Workspace layout (float offsets), 116.65 MB total (same proven footprint):
//   cv    [0, 12582912)
//   P_W [12582912,+2097152) P_U1T [14680064,+2097152) P_KT [16777216,+2097152)
//   h116  [18874368, 19660800)
//   decT  [19660800,+32768)  betaT [19693568,+32768)
//   wT    [19726336,+9437184): gw2T etc; after convgen:
//       P_D [19726336,+1048576) P_aL [20774912,+512) WoT [20807680,+2097152)
//       o16 [22904832,+2097152)  Qn [25001984,+2097152)
// ---------------------------------------------------------------------------
extern "C" void kernel_launch(void* const* d_in, const int* in_sizes, int n_in,
                              void* d_out, int out_size, void* d_ws, size_t ws_size,
                              hipStream_t stream)
{
    const float* x      = (const float*)d_in[0];
    const float* W_qkv  = (const float*)d_in[1];
    const float* W_ba   = (const float*)d_in[2];
    const float* gen_w1 = (const float*)d_in[3];
    const float* gen_w2 = (const float*)d_in[4];
    const float* gen_b2 = (const float*)d_in[5];
    const float* W_o    = (const float*)d_in[6];
    float* y  = (float*)d_out;
    float* wsf = (float*)d_ws;

    float*  cv    = wsf;
    bf16_t* x16   = (bf16_t*)wsf;
    bf16_t* u16   = (bf16_t*)(wsf + 12582912);
    bf16_t* h116  = (bf16_t*)(wsf + 18874368);
    float*  decT  = wsf + 19660800;
    float*  betaT = wsf + 19693568;
    bf16_t* wT    = (bf16_t*)(wsf + 19726336);
    bf16_t* P_W   = (bf16_t*)(wsf + 12582912);
    bf16_t* P_U1T = (bf16_t*)(wsf + 14680064);
    bf16_t* P_KT  = (bf16_t*)(wsf + 16777216);
    bf16_t* P_D   = (bf16_t*)(wsf + 19726336);
    float*  P_aL  = wsf + 20774912;
    bf16_t* WoT   = (bf16_t*)(wsf + 20807680);
    bf16_t* o16   = (bf16_t*)(wsf + 22904832);
    bf16_t* Qn    = (bf16_t*)(wsf + 25001984);

    dim3 blk(256);

    tcast<<<dim3(192, 64), blk, 0, stream>>>(W_qkv, wT, DM, CDIM);
    castk<<<dim3(4096), blk, 0, stream>>>(x, x16, (T_LEN * DM) / 4);
    mgemm<1, 6><<<dim3(768), blk, 0, stream>>>(x16, wT, nullptr, u16, T_LEN, CDIM, DM);
    ba_kernel<<<dim3(256), blk, 0, stream>>>(x, W_ba, betaT, decT);
    tcast<<<dim3(24, 192), blk, 0, stream>>>(gen_w1, wT, CDIM, GH);
    mgemm<2, 0><<<dim3(6, 16), blk, 0, stream>>>(u16, wT, nullptr, h116, T_LEN, GH, CDIM);
    tcast<<<dim3(768, 24), blk, 0, stream>>>(gen_w2, wT, GH, NOUT);
    convgen<<<dim3(3072), blk, 0, stream>>>(h116, wT, gen_b2, u16, cv);
    dr_phase1<<<dim3(512), blk, 0, stream>>>(cv, decT, betaT, P_W, P_U1T, P_KT, P_D, P_aL, Qn);
    tcast<<<dim3(64, 64), blk, 0, stream>>>(W_o, WoT, DM, DM);
    dr_phase2<<<dim3(32), blk, 0, stream>>>(Qn, P_W, P_U1T, P_KT, P_D, P_aL, o16);
    mgemm<0, 2><<<dim3(256), blk, 0, stream>>>(o16, WoT, y, nullptr, T_LEN, DM, DM);
}

// Round 8
// 792.653 us; speedup vs baseline: 2.7352x; 1.1802x over previous
//
#include <hip/hip_runtime.h>
#include <math.h>

#define T_LEN 2048
#define DM    2048
#define NH    16
#define HD    128
#define CDIM  6144
#define GH    768
#define NOUT  24576

typedef unsigned short bf16_t;
typedef unsigned int   uint32;
typedef __attribute__((ext_vector_type(8))) short short8;
typedef __attribute__((ext_vector_type(4))) float f32x4;

__device__ __forceinline__ float silu_f(float v) { return v / (1.f + __expf(-v)); }

__device__ __forceinline__ bf16_t f2bf(float f) {
    uint32 u = __float_as_uint(f);
    u = (u + 0x7fff + ((u >> 16) & 1)) >> 16;   // RNE
    return (bf16_t)u;
}
__device__ __forceinline__ float bf2f(bf16_t b) {
    return __uint_as_float(((uint32)b) << 16);
}
__device__ __forceinline__ uint32 pack2f(float a, float b) {
    return (uint32)f2bf(a) | ((uint32)f2bf(b) << 16);
}

// async global->LDS, 16B per lane; LDS dest = wave-uniform base + lane*16
#define GLL(gptr, lptr) \
  __builtin_amdgcn_global_load_lds((const __attribute__((address_space(1))) void*)(gptr), \
                                   (__attribute__((address_space(3))) void*)(lptr), 16, 0, 0)

// ---------------------------------------------------------------------------
// Transpose + cast: W [K][N] fp32 -> Wt [N][K] bf16
// ---------------------------------------------------------------------------
__global__ __launch_bounds__(256)
void tcast(const float* __restrict__ W, bf16_t* __restrict__ Wt, int K, int N)
{
    __shared__ float tile[32][33];
    const int n0 = blockIdx.x * 32, k0 = blockIdx.y * 32;
    const int c = threadIdx.x & 31, r = threadIdx.x >> 5;
#pragma unroll
    for (int i = 0; i < 4; i++)
        tile[r + i * 8][c] = W[(size_t)(k0 + r + i * 8) * N + n0 + c];
    __syncthreads();
#pragma unroll
    for (int i = 0; i < 4; i++)
        Wt[(size_t)(n0 + r + i * 8) * K + k0 + c] = f2bf(tile[c][r + i * 8]);
}

// elementwise fp32 -> bf16 (4 per thread)
__global__ __launch_bounds__(256)
void castk(const float* __restrict__ in, bf16_t* __restrict__ out, int n4)
{
    int i = blockIdx.x * 256 + threadIdx.x;
    if (i >= n4) return;
    float4 v = ((const float4*)in)[i];
    uint2 p;
    p.x = pack2f(v.x, v.y);
    p.y = pack2f(v.z, v.w);
    ((uint2*)out)[i] = p;
}

// ---------------------------------------------------------------------------
// bf16 MFMA GEMM (m97 structure): C[M,N] = A[M,K] @ Bt[N,K]^T
// ---------------------------------------------------------------------------
template<int EPI, int NPER>
__global__ __launch_bounds__(256)
void mgemm(const bf16_t* __restrict__ A, const bf16_t* __restrict__ Bt,
           float* __restrict__ C, bf16_t* __restrict__ C16,
           int M, int N, int K)
{
    __shared__ bf16_t As[4096];
    __shared__ bf16_t Bs[4096];
    const int tid = threadIdx.x;
    const int lane = tid & 63, w = tid >> 6;
    const int quad = lane >> 4, tl = lane & 15;
    int bm0, bn0;
    if (NPER == 0) { bm0 = blockIdx.y * 128; bn0 = blockIdx.x * 128; }
    else {
        int bx = blockIdx.x, xcd = bx & 7, seq = bx >> 3;
        bm0 = (seq & 15) * 128;
        bn0 = (xcd * NPER + (seq >> 4)) * 128;
    }
    const int wm = (w >> 1) * 64, wn = (w & 1) * 64;

    const bf16_t* a0 = A  + (size_t)(bm0 + (tid & 127)) * K + ((tid >> 7) << 3);
    const bf16_t* b0 = Bt + (size_t)(bn0 + (tid & 127)) * K + ((tid >> 7) << 3);
    bf16_t* asd0 = &As[w * 512];
    bf16_t* asd1 = &As[2048 + w * 512];
    bf16_t* bsd0 = &Bs[w * 512];
    bf16_t* bsd1 = &Bs[2048 + w * 512];

    f32x4 acc[4][4];
#pragma unroll
    for (int i = 0; i < 4; i++)
#pragma unroll
        for (int j = 0; j < 4; j++) { acc[i][j][0] = 0.f; acc[i][j][1] = 0.f; acc[i][j][2] = 0.f; acc[i][j][3] = 0.f; }

    for (int k0 = 0; k0 < K; k0 += 32) {
        __syncthreads();
        GLL(a0 + k0,      asd0);
        GLL(a0 + k0 + 16, asd1);
        GLL(b0 + k0,      bsd0);
        GLL(b0 + k0 + 16, bsd1);
        __syncthreads();
        short8 af[4], bfr[4];
#pragma unroll
        for (int mt = 0; mt < 4; mt++)
            af[mt] = *(const short8*)&As[(quad * 128 + wm + mt * 16 + tl) * 8];
#pragma unroll
        for (int nt = 0; nt < 4; nt++)
            bfr[nt] = *(const short8*)&Bs[(quad * 128 + wn + nt * 16 + tl) * 8];
#pragma unroll
        for (int mt = 0; mt < 4; mt++)
#pragma unroll
            for (int nt = 0; nt < 4; nt++)
                acc[mt][nt] = __builtin_amdgcn_mfma_f32_16x16x32_bf16(af[mt], bfr[nt], acc[mt][nt], 0, 0, 0);
    }

#pragma unroll
    for (int mt = 0; mt < 4; mt++) {
        int rbase = bm0 + wm + mt * 16 + quad * 4;
#pragma unroll
        for (int nt = 0; nt < 4; nt++) {
            int cg = bn0 + wn + nt * 16 + tl;
#pragma unroll
            for (int r = 0; r < 4; r++) {
                float v = acc[mt][nt][r];
                size_t idx = (size_t)(rbase + r) * N + cg;
                if (EPI == 0)      C[idx]   = v;
                else if (EPI == 1) C16[idx] = f2bf(v);
                else               C16[idx] = f2bf(silu_f(v));
            }
        }
    }
}

// ---------------------------------------------------------------------------
// Split-K GEMM for h1: A[2048][6144] @ Bt[768][6144]^T, 8 K-slices of 768.
// Grid (8, 6, 16): x = k-slice, y = N-tile, z = M-tile. fp32 partials out.
// (The 96-block non-split version ran 1 block/CU on 37% of CUs -> 98 TF.)
// ---------------------------------------------------------------------------
__global__ __launch_bounds__(256)
void mgemm_sk(const bf16_t* __restrict__ A, const bf16_t* __restrict__ Bt,
              float* __restrict__ Cp)
{
    const int K = CDIM, N = GH;
    __shared__ bf16_t As[4096];
    __shared__ bf16_t Bs[4096];
    const int tid = threadIdx.x;
    const int lane = tid & 63, w = tid >> 6;
    const int quad = lane >> 4, tl = lane & 15;
    const int ks = blockIdx.x;                // k-slice [0,8)
    const int bn0 = blockIdx.y * 128;
    const int bm0 = blockIdx.z * 128;
    const int wm = (w >> 1) * 64, wn = (w & 1) * 64;

    const bf16_t* a0 = A  + (size_t)(bm0 + (tid & 127)) * K + ((tid >> 7) << 3);
    const bf16_t* b0 = Bt + (size_t)(bn0 + (tid & 127)) * K + ((tid >> 7) << 3);
    bf16_t* asd0 = &As[w * 512];
    bf16_t* asd1 = &As[2048 + w * 512];
    bf16_t* bsd0 = &Bs[w * 512];
    bf16_t* bsd1 = &Bs[2048 + w * 512];

    f32x4 acc[4][4];
#pragma unroll
    for (int i = 0; i < 4; i++)
#pragma unroll
        for (int j = 0; j < 4; j++) { acc[i][j][0] = 0.f; acc[i][j][1] = 0.f; acc[i][j][2] = 0.f; acc[i][j][3] = 0.f; }

    const int kbeg = ks * 768, kend = kbeg + 768;
    for (int k0 = kbeg; k0 < kend; k0 += 32) {
        __syncthreads();
        GLL(a0 + k0,      asd0);
        GLL(a0 + k0 + 16, asd1);
        GLL(b0 + k0,      bsd0);
        GLL(b0 + k0 + 16, bsd1);
        __syncthreads();
        short8 af[4], bfr[4];
#pragma unroll
        for (int mt = 0; mt < 4; mt++)
            af[mt] = *(const short8*)&As[(quad * 128 + wm + mt * 16 + tl) * 8];
#pragma unroll
        for (int nt = 0; nt < 4; nt++)
            bfr[nt] = *(const short8*)&Bs[(quad * 128 + wn + nt * 16 + tl) * 8];
#pragma unroll
        for (int mt = 0; mt < 4; mt++)
#pragma unroll
            for (int nt = 0; nt < 4; nt++)
                acc[mt][nt] = __builtin_amdgcn_mfma_f32_16x16x32_bf16(af[mt], bfr[nt], acc[mt][nt], 0, 0, 0);
    }

    float* Cs = Cp + (size_t)ks * (T_LEN * GH);
#pragma unroll
    for (int mt = 0; mt < 4; mt++) {
        int rbase = bm0 + wm + mt * 16 + quad * 4;
#pragma unroll
        for (int nt = 0; nt < 4; nt++) {
            int cg = bn0 + wn + nt * 16 + tl;
#pragma unroll
            for (int r = 0; r < 4; r++)
                Cs[(size_t)(rbase + r) * GH + cg] = acc[mt][nt][r];
        }
    }
}

// reduce 8 split-K partials + silu + cast -> h1 bf16
__global__ __launch_bounds__(256)
void h1red(const float* __restrict__ Cp, bf16_t* __restrict__ h116)
{
    int i = blockIdx.x * 256 + threadIdx.x;   // [0, 393216) float4s
    const float4* p = (const float4*)Cp + i;
    float4 s = p[0];
#pragma unroll
    for (int k = 1; k < 8; k++) {
        float4 v = p[(size_t)k * 393216];
        s.x += v.x; s.y += v.y; s.z += v.z; s.w += v.w;
    }
    uint2 o;
    o.x = pack2f(silu_f(s.x), silu_f(s.y));
    o.y = pack2f(silu_f(s.z), silu_f(s.w));
    ((uint2*)h116)[i] = o;
}

// ---------------------------------------------------------------------------
// convgen: kern = h1 @ gen_w2 + b2 (MFMA), fused causal W=4 conv + silu.
// ---------------------------------------------------------------------------
__global__ __launch_bounds__(256)
void convgen(const bf16_t* __restrict__ A, const bf16_t* __restrict__ Bt,
             const float* __restrict__ b2, const bf16_t* __restrict__ u16c,
             float* __restrict__ cvout)
{
    const int K = GH;
    __shared__ __align__(16) char smraw[36864];
    bf16_t* As = (bf16_t*)smraw;
    bf16_t* Bs = As + 4096;
    float* uf   = (float*)smraw;              // [131][36]  (epilogue overlay)
    float* outs = (float*)(smraw + 18880);    // [128][33]

    const int tid = threadIdx.x;
    const int lane = tid & 63, w = tid >> 6;
    const int quad = lane >> 4, tl = lane & 15;
    const int bx = blockIdx.x, xcd = bx & 7, seq = bx >> 3;
    const int bm0 = (seq & 15) * 128;
    const int bn0 = (xcd * 24 + (seq >> 4)) * 128;
    const int wm = (w >> 1) * 64, wn = (w & 1) * 64;

    const bf16_t* a0 = A  + (size_t)(bm0 + (tid & 127)) * K + ((tid >> 7) << 3);
    const bf16_t* b0 = Bt + (size_t)(bn0 + (tid & 127)) * K + ((tid >> 7) << 3);
    bf16_t* asd0 = &As[w * 512];
    bf16_t* asd1 = &As[2048 + w * 512];
    bf16_t* bsd0 = &Bs[w * 512];
    bf16_t* bsd1 = &Bs[2048 + w * 512];

    f32x4 acc[4][4];
#pragma unroll
    for (int i = 0; i < 4; i++)
#pragma unroll
        for (int j = 0; j < 4; j++) { acc[i][j][0] = 0.f; acc[i][j][1] = 0.f; acc[i][j][2] = 0.f; acc[i][j][3] = 0.f; }

    for (int k0 = 0; k0 < K; k0 += 32) {
        __syncthreads();
        GLL(a0 + k0,      asd0);
        GLL(a0 + k0 + 16, asd1);
        GLL(b0 + k0,      bsd0);
        GLL(b0 + k0 + 16, bsd1);
        __syncthreads();
        short8 af[4], bfr[4];
#pragma unroll
        for (int mt = 0; mt < 4; mt++)
            af[mt] = *(const short8*)&As[(quad * 128 + wm + mt * 16 + tl) * 8];
#pragma unroll
        for (int nt = 0; nt < 4; nt++)
            bfr[nt] = *(const short8*)&Bs[(quad * 128 + wn + nt * 16 + tl) * 8];
#pragma unroll
        for (int mt = 0; mt < 4; mt++)
#pragma unroll
            for (int nt = 0; nt < 4; nt++)
                acc[mt][nt] = __builtin_amdgcn_mfma_f32_16x16x32_bf16(af[mt], bfr[nt], acc[mt][nt], 0, 0, 0);
    }
    __syncthreads();   // fragments consumed; overlay As/Bs with uf/outs

    const int d0 = bn0 >> 2;
    for (int i = tid; i < 131 * 8; i += 256) {
        int row = i >> 3, seg = i & 7;
        int t = bm0 - 3 + row;
        float* dst = &uf[row * 36 + seg * 4];
        if (t >= 0) {
            uint2 p = *(const uint2*)&u16c[(size_t)t * CDIM + d0 + seg * 4];
            dst[0] = bf2f((bf16_t)(p.x & 0xffff));
            dst[1] = bf2f((bf16_t)(p.x >> 16));
            dst[2] = bf2f((bf16_t)(p.y & 0xffff));
            dst[3] = bf2f((bf16_t)(p.y >> 16));
        } else {
            dst[0] = 0.f; dst[1] = 0.f; dst[2] = 0.f; dst[3] = 0.f;
        }
    }
    __syncthreads();

    const int wi = tl & 3;
#pragma unroll
    for (int nt = 0; nt < 4; nt++) {
        int n = bn0 + wn + nt * 16 + tl;
        float b2v = b2[n];
        int dloc = (wn >> 2) + nt * 4 + (tl >> 2);
#pragma unroll
        for (int mt = 0; mt < 4; mt++) {
            int trl = wm + mt * 16 + quad * 4;
#pragma unroll
            for (int r = 0; r < 4; r++) {
                float p = (acc[mt][nt][r] + b2v) * uf[(trl + r + wi) * 36 + dloc];
                p += __shfl_xor(p, 1);
                p += __shfl_xor(p, 2);
                if (wi == 0) outs[(trl + r) * 33 + dloc] = p;
            }
        }
    }
    __syncthreads();

    for (int i = tid; i < 4096; i += 256) {
        int row = i >> 5, col = i & 31;
        cvout[(size_t)(bm0 + row) * CDIM + d0 + col] = silu_f(outs[row * 33 + col]);
    }
}

// ---------------------------------------------------------------------------
// ba: beta=sigmoid(b), decay=sigmoid(-a); outputs transposed [H][T]
// ---------------------------------------------------------------------------
__global__ __launch_bounds__(256)
void ba_kernel(const float* __restrict__ x, const float* __restrict__ Wba,
               float* __restrict__ betaT, float* __restrict__ decT)
{
    const int t = blockIdx.x * 8 + (threadIdx.x >> 5);
    const int c = threadIdx.x & 31;
    const float* xr = x + (size_t)t * DM;
    float acc = 0.f;
#pragma unroll 4
    for (int k0 = 0; k0 < DM; k0 += 4) {
        float4 xv = *(const float4*)&xr[k0];
        acc = fmaf(xv.x, Wba[(k0 + 0) * 32 + c], acc);
        acc = fmaf(xv.y, Wba[(k0 + 1) * 32 + c], acc);
        acc = fmaf(xv.z, Wba[(k0 + 2) * 32 + c], acc);
        acc = fmaf(xv.w, Wba[(k0 + 3) * 32 + c], acc);
    }
    float val = 1.f / (1.f + __expf((c < 16) ? -acc : acc));
    if (c < 16) betaT[(size_t)c * T_LEN + t] = val;
    else        decT[(size_t)(c - 16) * T_LEN + t] = val;
}

// ===========================================================================
// Chunked gated delta rule (UT transform), L = 64.  (unchanged from R6)
// ===========================================================================
__global__ __launch_bounds__(256)
void dr_phase1(const float* __restrict__ cv, const float* __restrict__ decT,
               const float* __restrict__ betaT,
               bf16_t* __restrict__ P_W, bf16_t* __restrict__ P_U1T,
               bf16_t* __restrict__ P_KT, bf16_t* __restrict__ P_D,
               float* __restrict__ P_aL, bf16_t* __restrict__ Qn)
{
    __shared__ float kfn[64 * 132];     // normalized k, fp32
    __shared__ float A_ls[64 * 68];     // A[s][r]
    __shared__ bf16_t D16s[64 * 68];    // D staging (bf16)
    __shared__ float csL[64], betaL[64], eaL[64], ebL[64], rnk[64];

    const int ch = blockIdx.x, h = ch >> 5, c = ch & 31;
    const int t0 = c * 64;
    const int tid = threadIdx.x, w = tid >> 6, lane = tid & 63;
    const int quad = lane >> 4, tl = lane & 15;

    const float* kg = cv + (size_t)t0 * CDIM + NH * HD + h * HD;
    const float* qg = cv + (size_t)t0 * CDIM + h * HD;
    const float* vg = cv + (size_t)t0 * CDIM + 2 * NH * HD + h * HD;

#pragma unroll
    for (int i = 0; i < 8; i++) {
        int idx = tid + 256 * i;
        int t = idx >> 5, c4 = (idx & 31) * 4;
        *(float4*)&kfn[t * 132 + c4] = *(const float4*)&kg[(size_t)t * CDIM + c4];
    }
    if (tid < 64) {
        float dec = decT[(size_t)h * T_LEN + t0 + tid];
        float csum = __logf(dec);
#pragma unroll
        for (int off = 1; off < 64; off <<= 1) {
            float o = __shfl_up(csum, off);
            if (tid >= off) csum += o;
        }
        csL[tid]   = csum;
        eaL[tid]   = __expf(csum);
        betaL[tid] = betaT[(size_t)h * T_LEN + t0 + tid];
        float c63 = __shfl(csum, 63);
        ebL[tid]  = __expf(c63 - csum);
    }
    __syncthreads();
    if (tid == 63) P_aL[ch] = __expf(csL[63]);

    {
        int t = tid >> 2, p = tid & 3;
        float ss = 0.f;
#pragma unroll
        for (int j = 0; j < 8; j++) {
            float4 v = *(const float4*)&kfn[t * 132 + p * 32 + j * 4];
            ss += v.x * v.x + v.y * v.y + v.z * v.z + v.w * v.w;
        }
        ss += __shfl_xor(ss, 1);
        ss += __shfl_xor(ss, 2);
        if (p == 0) rnk[t] = rsqrtf(ss + 1e-6f);
    }
    __syncthreads();
#pragma unroll
    for (int i = 0; i < 8; i++) {
        int idx = tid + 256 * i;
        int t = idx >> 5, c4 = (idx & 31) * 4;
        float4 v = *(float4*)&kfn[t * 132 + c4];
        float rs = rnk[t];
        v.x *= rs; v.y *= rs; v.z *= rs; v.w *= rs;
        *(float4*)&kfn[t * 132 + c4] = v;
    }
    __syncthreads();

    const int row = 16 * w + tl;
    float qv[4][8];
    float ssq = 0.f;
#pragma unroll
    for (int kk = 0; kk < 4; kk++) {
        const float* qp = &qg[(size_t)row * CDIM + 32 * kk + 8 * quad];
        *(float4*)&qv[kk][0] = *(const float4*)qp;
        *(float4*)&qv[kk][4] = *(const float4*)(qp + 4);
#pragma unroll
        for (int j = 0; j < 8; j++) ssq += qv[kk][j] * qv[kk][j];
    }
    ssq += __shfl_xor(ssq, 16);
    ssq += __shfl_xor(ssq, 32);
    const float qsc = rsqrtf(ssq + 1e-6f) * 0.08838834764831845f;
    const float qe  = qsc * eaL[row];

    short8 xqh[4], xql[4], xkh[4], xkl[4];
    {
        bf16_t* Qch = Qn + (size_t)ch * 8192;
#pragma unroll
        for (int kk = 0; kk < 4; kk++) {
            short8 qn8;
#pragma unroll
            for (int j = 0; j < 8; j++) {
                float qx = qv[kk][j] * qsc;
                bf16_t hh = f2bf(qx);
                xqh[kk][j] = (short)hh;
                xql[kk][j] = (short)f2bf(qx - bf2f(hh));
                qn8[j] = (short)f2bf(qv[kk][j] * qe);
            }
            *(short8*)&Qch[((4 * kk + quad) * 64 + row) * 8] = qn8;
        }
#pragma unroll
        for (int kk = 0; kk < 4; kk++) {
            float kv[8];
            *(float4*)&kv[0] = *(const float4*)&kfn[row * 132 + 32 * kk + 8 * quad];
            *(float4*)&kv[4] = *(const float4*)&kfn[row * 132 + 32 * kk + 8 * quad + 4];
#pragma unroll
            for (int j = 0; j < 8; j++) {
                bf16_t hh = f2bf(kv[j]);
                xkh[kk][j] = (short)hh;
                xkl[kk][j] = (short)f2bf(kv[j] - bf2f(hh));
            }
        }
    }

    f32x4 aK[4], aQ[4];
#pragma unroll
    for (int j = 0; j < 4; j++)
#pragma unroll
        for (int r = 0; r < 4; r++) { aK[j][r] = 0.f; aQ[j][r] = 0.f; }
#pragma unroll
    for (int tj = 0; tj < 4; tj++) {
#pragma unroll
        for (int kk = 0; kk < 4; kk++) {
            float yv[8];
            int yoff = (16 * tj + tl) * 132 + 32 * kk + 8 * quad;
            *(float4*)&yv[0] = *(const float4*)&kfn[yoff];
            *(float4*)&yv[4] = *(const float4*)&kfn[yoff + 4];
            short8 yh, yl;
#pragma unroll
            for (int j = 0; j < 8; j++) {
                bf16_t hh = f2bf(yv[j]);
                yh[j] = (short)hh;
                yl[j] = (short)f2bf(yv[j] - bf2f(hh));
            }
            aK[tj] = __builtin_amdgcn_mfma_f32_16x16x32_bf16(xkh[kk], yh, aK[tj], 0, 0, 0);
            aK[tj] = __builtin_amdgcn_mfma_f32_16x16x32_bf16(xkh[kk], yl, aK[tj], 0, 0, 0);
            aK[tj] = __builtin_amdgcn_mfma_f32_16x16x32_bf16(xkl[kk], yh, aK[tj], 0, 0, 0);
            aQ[tj] = __builtin_amdgcn_mfma_f32_16x16x32_bf16(xqh[kk], yh, aQ[tj], 0, 0, 0);
            aQ[tj] = __builtin_amdgcn_mfma_f32_16x16x32_bf16(xqh[kk], yl, aQ[tj], 0, 0, 0);
            aQ[tj] = __builtin_amdgcn_mfma_f32_16x16x32_bf16(xql[kk], yh, aQ[tj], 0, 0, 0);
        }
    }
#pragma unroll
    for (int tj = 0; tj < 4; tj++) {
#pragma unroll
        for (int r = 0; r < 4; r++) {
            int s  = 16 * w + 4 * quad + r;
            int rr = 16 * tj + tl;
            float e = __expf(csL[s] - csL[rr]);
            A_ls[s * 68 + rr] = (s > rr) ? betaL[s] * e * aK[tj][r] : 0.f;
            D16s[s * 68 + rr] = (s >= rr) ? f2bf(e * aQ[tj][r]) : (bf16_t)0;
        }
    }
    __syncthreads();

    float bb[64];
    if (tid < 128) {
        int j = tid;
#pragma unroll
        for (int s = 0; s < 64; s++) bb[s] = betaL[s] * vg[(size_t)s * CDIM + j];
    } else {
        int dk = tid - 128;
#pragma unroll
        for (int s = 0; s < 64; s++)
            bb[s] = betaL[s] * eaL[s] * kfn[s * 132 + dk];
    }
#pragma unroll
    for (int r4 = 0; r4 < 64; r4 += 4) {
        float u0 = bb[r4];
        float u1 = bb[r4 + 1] - A_ls[(r4 + 1) * 68 + r4] * u0;
        float u2 = bb[r4 + 2] - A_ls[(r4 + 2) * 68 + r4] * u0 - A_ls[(r4 + 2) * 68 + r4 + 1] * u1;
        float u3 = bb[r4 + 3] - A_ls[(r4 + 3) * 68 + r4] * u0 - A_ls[(r4 + 3) * 68 + r4 + 1] * u1
                              - A_ls[(r4 + 3) * 68 + r4 + 2] * u2;
        bb[r4] = u0; bb[r4 + 1] = u1; bb[r4 + 2] = u2; bb[r4 + 3] = u3;
#pragma unroll
        for (int s = r4 + 4; s < 64; s++) {
            float4 a4 = *(const float4*)&A_ls[s * 68 + r4];
            bb[s] -= a4.x * u0 + a4.y * u1 + a4.z * u2 + a4.w * u3;
        }
    }

    {
        uint32* gK = (uint32*)(P_KT + (size_t)ch * 8192);
#pragma unroll
        for (int i = 0; i < 16; i++) {
            int u = tid * 16 + i;
            int soct = u >> 9, dk = (u >> 2) & 127, s = soct * 8 + (u & 3) * 2;
            gK[u] = pack2f(ebL[s] * kfn[s * 132 + dk], ebL[s + 1] * kfn[(s + 1) * 132 + dk]);
        }
    }
    {
        uint32* gD = (uint32*)(P_D + (size_t)ch * 4096);
#pragma unroll
        for (int i = 0; i < 8; i++) {
            int u = tid * 8 + i;
            int soct = u >> 8, t = (u >> 2) & 63, s = soct * 8 + (u & 3) * 2;
            gD[u] = (uint32)D16s[t * 68 + s] | ((uint32)D16s[t * 68 + s + 1] << 16);
        }
    }
    __syncthreads();
    float* wtmp = kfn;
    bf16_t* uS = (bf16_t*)A_ls;
    if (tid < 128) {
        int g2 = tid >> 6, vloc = tid & 63;
        int base = g2 * 4096 + (vloc >> 4) * 1024 + ((vloc >> 2) & 3) * 256 + (vloc & 3);
#pragma unroll
        for (int s = 0; s < 64; s++)
            uS[base + (s & 15) * 16 + (s >> 4) * 4] = f2bf(bb[s]);
    } else {
        int dk = tid - 128;
#pragma unroll
        for (int s = 0; s < 64; s++) wtmp[s * 132 + dk] = bb[s];
    }
    __syncthreads();
    {
        uint32* gW = (uint32*)(P_W + (size_t)ch * 8192);
#pragma unroll
        for (int i = 0; i < 16; i++) {
            int u = tid * 16 + i;
            int koct = u >> 8, s = (u >> 2) & 63, k = koct * 8 + (u & 3) * 2;
            gW[u] = pack2f(wtmp[s * 132 + k], wtmp[s * 132 + k + 1]);
        }
        uint32* gU = (uint32*)(P_U1T + (size_t)ch * 8192);
        const uint32* uS32 = (const uint32*)uS;
#pragma unroll
        for (int i = 0; i < 16; i++) gU[tid * 16 + i] = uS32[tid * 16 + i];
    }
}

__global__ __launch_bounds__(256, 1)
void dr_phase2(const bf16_t* __restrict__ Qn,
               const bf16_t* __restrict__ P_W, const bf16_t* __restrict__ P_U1T,
               const bf16_t* __restrict__ P_KT, const bf16_t* __restrict__ P_D,
               const float* __restrict__ P_aL, bf16_t* __restrict__ o16)
{
    __shared__ bf16_t Ws[2][8192];
    __shared__ bf16_t Ks[2][8192];
    __shared__ bf16_t Ds[2][4096];
    __shared__ unsigned short Z16[64 * 136];
    __shared__ unsigned short uT16[64 * 72];

    const int h = blockIdx.x >> 1, g = blockIdx.x & 1, vbase = g * 64;
    const int tid = threadIdx.x, w = tid >> 6, lane = tid & 63;
    const int quad = lane >> 4, tl = lane & 15;
    const int trow = 16 * w + tl;

    for (int i = tid; i < 64 * 136 / 2; i += 256) ((uint32*)Z16)[i] = 0;

    f32x4 Zacc[8];
#pragma unroll
    for (int i = 0; i < 8; i++)
#pragma unroll
        for (int r = 0; r < 4; r++) Zacc[i][r] = 0.f;

    short8 qpf0[4], qpf1[4], upf0[2], upf1[2];
    float aL0, aL1;

    {
        const int c0 = h * 32;
        const bf16_t* gp = P_W + (size_t)c0 * 8192;
#pragma unroll
        for (int i = 0; i < 4; i++) GLL(gp + (w * 4 + i) * 512 + lane * 8, &Ws[0][(w * 4 + i) * 512]);
        gp = P_KT + (size_t)c0 * 8192;
#pragma unroll
        for (int i = 0; i < 4; i++) GLL(gp + (w * 4 + i) * 512 + lane * 8, &Ks[0][(w * 4 + i) * 512]);
        gp = P_D + (size_t)c0 * 4096;
#pragma unroll
        for (int i = 0; i < 2; i++) GLL(gp + (w * 2 + i) * 512 + lane * 8, &Ds[0][(w * 2 + i) * 512]);
        const bf16_t* pQ = Qn + (size_t)c0 * 8192;
#pragma unroll
        for (int kk = 0; kk < 4; kk++) qpf0[kk] = *(const short8*)&pQ[((4 * kk + quad) * 64 + trow) * 8];
        const bf16_t* pU = P_U1T + (size_t)c0 * 8192 + g * 4096 + tid * 16;
        upf0[0] = *(const short8*)&pU[0];
        upf0[1] = *(const short8*)&pU[8];
        aL0 = P_aL[c0];
    }
    __syncthreads();

#define CHUNK(C, S, SN)                                                             \
    {                                                                               \
        const int t0c = (C) * 64;                                                   \
        if ((C) + 1 < 32) {                                                         \
            const int cn = h * 32 + (C) + 1;                                        \
            const bf16_t* gp = P_W + (size_t)cn * 8192;                             \
            _Pragma("unroll")                                                       \
            for (int i = 0; i < 4; i++)                                             \
                GLL(gp + (w * 4 + i) * 512 + lane * 8, &Ws[SN][(w * 4 + i) * 512]); \
            gp = P_KT + (size_t)cn * 8192;                                          \
            _Pragma("unroll")                                                       \
            for (int i = 0; i < 4; i++)                                             \
                GLL(gp + (w * 4 + i) * 512 + lane * 8, &Ks[SN][(w * 4 + i) * 512]); \
            gp = P_D + (size_t)cn * 4096;                                           \
            _Pragma("unroll")                                                       \
            for (int i = 0; i < 2; i++)                                             \
                GLL(gp + (w * 2 + i) * 512 + lane * 8, &Ds[SN][(w * 2 + i) * 512]); \
            const bf16_t* pQ = Qn + (size_t)cn * 8192;                              \
            _Pragma("unroll")                                                       \
            for (int kk = 0; kk < 4; kk++)                                          \
                qpf##SN[kk] = *(const short8*)&pQ[((4 * kk + quad) * 64 + trow) * 8]; \
            const bf16_t* pU = P_U1T + (size_t)cn * 8192 + g * 4096 + tid * 16;     \
            upf##SN[0] = *(const short8*)&pU[0];                                    \
            upf##SN[1] = *(const short8*)&pU[8];                                    \
            aL##SN = P_aL[cn];                                                      \
        }                                                                           \
        f32x4 au[4];                                                                \
        _Pragma("unroll")                                                           \
        for (int j = 0; j < 4; j++)                                                 \
            { au[j][0] = 0.f; au[j][1] = 0.f; au[j][2] = 0.f; au[j][3] = 0.f; }     \
        short8 zf[4];                                                               \
        _Pragma("unroll")                                                           \
        for (int kk = 0; kk < 4; kk++)                                              \
            zf[kk] = *(const short8*)&Z16[trow * 136 + 32 * kk + 8 * quad];         \
        _Pragma("unroll")                                                           \
        for (int tj = 0; tj < 4; tj++)                                              \
            _Pragma("unroll")                                                       \
            for (int kk = 0; kk < 4; kk++) {                                        \
                short8 wf = *(const short8*)&Ws[S][((4 * kk + quad) * 64 + 16 * tj + tl) * 8]; \
                au[tj] = __builtin_amdgcn_mfma_f32_16x16x32_bf16(zf[kk], wf, au[tj], 0, 0, 0); \
            }                                                                       \
        _Pragma("unroll")                                                           \
        for (int tj = 0; tj < 4; tj++)                                              \
            _Pragma("unroll")                                                       \
            for (int r = 0; r < 4; r++) {                                           \
                int v = 16 * w + 4 * quad + r, sc = 16 * tj + tl;                   \
                float u1 = bf2f((bf16_t)(unsigned short)upf##S[(tj * 4 + r) >> 3][(tj * 4 + r) & 7]); \
                uT16[v * 72 + sc] = f2bf(u1 - au[tj][r]);                           \
            }                                                                       \
        __syncthreads();                                                            \
        f32x4 ao[4];                                                                \
        _Pragma("unroll")                                                           \
        for (int j = 0; j < 4; j++)                                                 \
            { ao[j][0] = 0.f; ao[j][1] = 0.f; ao[j][2] = 0.f; ao[j][3] = 0.f; }     \
        _Pragma("unroll")                                                           \
        for (int kk = 0; kk < 4; kk++) {                                            \
            _Pragma("unroll")                                                       \
            for (int tj = 0; tj < 4; tj++) {                                        \
                short8 zb = *(const short8*)&Z16[(16 * tj + tl) * 136 + 32 * kk + 8 * quad]; \
                ao[tj] = __builtin_amdgcn_mfma_f32_16x16x32_bf16(qpf##S[kk], zb, ao[tj], 0, 0, 0); \
            }                                                                       \
        }                                                                           \
        _Pragma("unroll")                                                           \
        for (int k2 = 0; k2 < 2; k2++) {                                            \
            short8 df = *(const short8*)&Ds[S][((4 * k2 + quad) * 64 + trow) * 8];  \
            _Pragma("unroll")                                                       \
            for (int tj = 0; tj < 4; tj++) {                                        \
                short8 ub = *(const short8*)&uT16[(16 * tj + tl) * 72 + 32 * k2 + 8 * quad]; \
                ao[tj] = __builtin_amdgcn_mfma_f32_16x16x32_bf16(df, ub, ao[tj], 0, 0, 0); \
            }                                                                       \
        }                                                                           \
        _Pragma("unroll")                                                           \
        for (int tj = 0; tj < 4; tj++)                                              \
            _Pragma("unroll")                                                       \
            for (int r = 0; r < 4; r++) {                                           \
                int t = 16 * w + 4 * quad + r, v = 16 * tj + tl;                    \
                o16[(size_t)(t0c + t) * DM + h * HD + vbase + v] = f2bf(ao[tj][r]); \
            }                                                                       \
        __syncthreads();                                                            \
        _Pragma("unroll")                                                           \
        for (int td = 0; td < 8; td++)                                              \
            _Pragma("unroll")                                                       \
            for (int r = 0; r < 4; r++) Zacc[td][r] *= aL##S;                       \
        _Pragma("unroll")                                                           \
        for (int k2 = 0; k2 < 2; k2++) {                                            \
            short8 uf = *(const short8*)&uT16[trow * 72 + 32 * k2 + 8 * quad];      \
            _Pragma("unroll")                                                       \
            for (int td = 0; td < 8; td++) {                                        \
                short8 kf = *(const short8*)&Ks[S][((4 * k2 + quad) * 128 + 16 * td + tl) * 8]; \
                Zacc[td] = __builtin_amdgcn_mfma_f32_16x16x32_bf16(uf, kf, Zacc[td], 0, 0, 0); \
            }                                                                       \
        }                                                                           \
        _Pragma("unroll")                                                           \
        for (int td = 0; td < 8; td++)                                              \
            _Pragma("unroll")                                                       \
            for (int r = 0; r < 4; r++) {                                           \
                int v = 16 * w + 4 * quad + r, dk = 16 * td + tl;                   \
                Z16[v * 136 + dk] = f2bf(Zacc[td][r]);                              \
            }                                                                       \
        __syncthreads();                                                            \
    }

    for (int cc = 0; cc < 32; cc += 2) {
        CHUNK(cc, 0, 1);
        CHUNK(cc + 1, 1, 0);
    }
#undef CHUNK
}

// ---------------------------------------------------------------------------
// Workspace layout (float offsets), 116.65 MB total (same proven footprint):
//   cv    [0, 12582912)   -- also h1 split-K partials Cp (dead window) --
//   P_W [12582912,+2097152) P_U1T [14680064,+2097152) P_KT [16777216,+2097152)
//   h116  [18874368, 19660800)
//   decT  [19660800,+32768)  betaT [19693568,+32768)
//   wT    [19726336,+9437184): gw2T etc; after convgen:
//       P_D [19726336,+1048576) P_aL [20774912,+512) WoT [20807680,+2097152)
//       o16 [22904832,+2097152)  Qn [25001984,+2097152)
// ---------------------------------------------------------------------------
extern "C" void kernel_launch(void* const* d_in, const int* in_sizes, int n_in,
                              void* d_out, int out_size, void* d_ws, size_t ws_size,
                              hipStream_t stream)
{
    const float* x      = (const float*)d_in[0];
    const float* W_qkv  = (const float*)d_in[1];
    const float* W_ba   = (const float*)d_in[2];
    const float* gen_w1 = (const float*)d_in[3];
    const float* gen_w2 = (const float*)d_in[4];
    const float* gen_b2 = (const float*)d_in[5];
    const float* W_o    = (const float*)d_in[6];
    float* y  = (float*)d_out;
    float* wsf = (float*)d_ws;

    float*  cv    = wsf;
    float*  Cp    = wsf;                           // h1 partials (cv dead window)
    bf16_t* x16   = (bf16_t*)wsf;
    bf16_t* u16   = (bf16_t*)(wsf + 12582912);
    bf16_t* h116  = (bf16_t*)(wsf + 18874368);
    float*  decT  = wsf + 19660800;
    float*  betaT = wsf + 19693568;
    bf16_t* wT    = (bf16_t*)(wsf + 19726336);
    bf16_t* P_W   = (bf16_t*)(wsf + 12582912);
    bf16_t* P_U1T = (bf16_t*)(wsf + 14680064);
    bf16_t* P_KT  = (bf16_t*)(wsf + 16777216);
    bf16_t* P_D   = (bf16_t*)(wsf + 19726336);
    float*  P_aL  = wsf + 20774912;
    bf16_t* WoT   = (bf16_t*)(wsf + 20807680);
    bf16_t* o16   = (bf16_t*)(wsf + 22904832);
    bf16_t* Qn    = (bf16_t*)(wsf + 25001984);

    dim3 blk(256);

    tcast<<<dim3(192, 64), blk, 0, stream>>>(W_qkv, wT, DM, CDIM);
    castk<<<dim3(4096), blk, 0, stream>>>(x, x16, (T_LEN * DM) / 4);
    mgemm<1, 6><<<dim3(768), blk, 0, stream>>>(x16, wT, nullptr, u16, T_LEN, CDIM, DM);
    ba_kernel<<<dim3(256), blk, 0, stream>>>(x, W_ba, betaT, decT);
    tcast<<<dim3(24, 192), blk, 0, stream>>>(gen_w1, wT, CDIM, GH);
    // h1 = silu(u @ gen_w1) via split-K (8 slices) + reduce
    mgemm_sk<<<dim3(8, 6, 16), blk, 0, stream>>>(u16, wT, Cp);
    h1red<<<dim3(1536), blk, 0, stream>>>(Cp, h116);
    tcast<<<dim3(768, 24), blk, 0, stream>>>(gen_w2, wT, GH, NOUT);
    convgen<<<dim3(3072), blk, 0, stream>>>(h116, wT, gen_b2, u16, cv);
    dr_phase1<<<dim3(512), blk, 0, stream>>>(cv, decT, betaT, P_W, P_U1T, P_KT, P_D, P_aL, Qn);
    tcast<<<dim3(64, 64), blk, 0, stream>>>(W_o, WoT, DM, DM);
    dr_phase2<<<dim3(32), blk, 0, stream>>>(Qn, P_W, P_U1T, P_KT, P_D, P_aL, o16);
    mgemm<0, 2><<<dim3(256), blk, 0, stream>>>(o16, WoT, y, nullptr, T_LEN, DM, DM);
}